// Round 1
// baseline (1540.200 us; speedup 1.0000x reference)
//
#include <hip/hip_runtime.h>
#include <stdint.h>

#define DM 2048
#define NH 16
#define HD 128
#define BB 4
#define SS 2048
#define BS (BB*SS)      // 8192 rows
#define NQKV (3*DM)     // 6144

typedef __bf16 bf16_t;
typedef __attribute__((ext_vector_type(8))) __bf16 bf16x8;
typedef __attribute__((ext_vector_type(4))) float f32x4;
typedef __attribute__((ext_vector_type(4))) float float4v;
typedef __attribute__((ext_vector_type(4))) unsigned int uint4v;
typedef __attribute__((ext_vector_type(4))) unsigned short ushort4v;

__device__ __forceinline__ unsigned short f2bf(float f) {
  unsigned u = __float_as_uint(f);
  u += 0x7fffu + ((u >> 16) & 1u);
  return (unsigned short)(u >> 16);
}

// ---------------- fp32 -> bf16 conversion (vectorized, grid-stride) -------
__global__ void conv_f32_bf16(const float* __restrict__ in,
                              unsigned short* __restrict__ out, int n4) {
  int i = blockIdx.x * blockDim.x + threadIdx.x;
  int stride = gridDim.x * blockDim.x;
  for (; i < n4; i += stride) {
    float4v v = ((const float4v*)in)[i];
    ushort4v o;
    o.x = f2bf(v.x); o.y = f2bf(v.y); o.z = f2bf(v.z); o.w = f2bf(v.w);
    ((ushort4v*)out)[i] = o;
  }
}

// ---------------- GEMM C = A * B^T  (A [M,K] bf16, B [N,K] bf16) ----------
// 128x128 tile, 4 waves (2x2 of 64x64), BK=32, mfma 16x16x32 bf16.
// MODE 0: C -> fp32 row-major [M,N]
// MODE 1: QKV scatter: n<2048 -> q bf16 [b,h,s,d]; <4096 -> k fp32; else v fp32
template<int MODE>
__global__ void gemm_bt(const bf16_t* __restrict__ A, const bf16_t* __restrict__ Bm,
                        const int M, const int N, const int K,
                        float* __restrict__ Cf,
                        bf16_t* __restrict__ qbf,
                        float* __restrict__ kf, float* __restrict__ vf) {
  __shared__ bf16_t As[128 * 32];
  __shared__ bf16_t Bs[128 * 32];
  const int t = threadIdx.x;
  const int w = t >> 6, lane = t & 63;
  const int wm = (w >> 1) * 64, wn = (w & 1) * 64;
  const int row0 = blockIdx.x * 128, col0 = blockIdx.y * 128;
  const int fr = lane & 15, fq = lane >> 4;

  f32x4 acc[4][4] = {};

  for (int kk = 0; kk < K; kk += 32) {
    // stage A,B tiles: thread does 2 x 16B per tile; LDS [row][32] with
    // chunk-XOR swizzle: chunk ^= (row&3)
#pragma unroll
    for (int j = 0; j < 2; ++j) {
      int idx = j * 256 + t;           // 16B-unit index 0..511
      int r = idx >> 2, c = idx & 3;   // row 0..127, 16B chunk 0..3
      uint4v dA = *(const uint4v*)(A + (size_t)(row0 + r) * K + kk + c * 8);
      uint4v dB = *(const uint4v*)(Bm + (size_t)(col0 + r) * K + kk + c * 8);
      int so = r * 32 + ((c ^ (r & 3)) * 8);
      *(uint4v*)(As + so) = dA;
      *(uint4v*)(Bs + so) = dB;
    }
    __syncthreads();
    bf16x8 af[4], bfv[4];
#pragma unroll
    for (int f = 0; f < 4; ++f) {
      int ra = wm + f * 16 + fr;
      af[f] = *(const bf16x8*)(As + ra * 32 + ((fq ^ (ra & 3)) * 8));
      int rb = wn + f * 16 + fr;
      bfv[f] = *(const bf16x8*)(Bs + rb * 32 + ((fq ^ (rb & 3)) * 8));
    }
#pragma unroll
    for (int i = 0; i < 4; ++i)
#pragma unroll
      for (int jn = 0; jn < 4; ++jn)
        acc[i][jn] = __builtin_amdgcn_mfma_f32_16x16x32_bf16(af[i], bfv[jn], acc[i][jn], 0, 0, 0);
    __syncthreads();
  }

  // epilogue: C/D layout col=lane&15, row=(lane>>4)*4+reg (m89/m91-verified)
#pragma unroll
  for (int i = 0; i < 4; ++i) {
#pragma unroll
    for (int jn = 0; jn < 4; ++jn) {
#pragma unroll
      for (int r = 0; r < 4; ++r) {
        int m = row0 + wm + i * 16 + fq * 4 + r;
        int n = col0 + wn + jn * 16 + fr;
        float v = acc[i][jn][r];
        if (MODE == 0) {
          Cf[(size_t)m * N + n] = v;
        } else {
          int b = m >> 11, s = m & 2047;
          if (n < DM) {
            int h = n >> 7, d = n & 127;
            qbf[(((size_t)(b * NH + h)) * SS + s) * HD + d] = (bf16_t)v;
          } else if (n < 2 * DM) {
            int nn = n - DM, h = nn >> 7, d = nn & 127;
            kf[(((size_t)(b * NH + h)) * SS + s) * HD + d] = v;
          } else {
            int nn = n - 2 * DM, h = nn >> 7, d = nn & 127;
            vf[(((size_t)(b * NH + h)) * SS + s) * HD + d] = v;
          }
        }
      }
    }
  }
}

// ---------------- causal flash attention ----------------------------------
// grid (32 qtiles, 64 bh), 256 thr = 4 waves; wave w owns q-rows q0+w*16..+15.
// K LDS [64][128] bf16 (chunk^=(row&7) swizzle), V LDS transposed [128][64],
// P per-wave [16][64]. KVTILE=64, online softmax fp32.
__global__ void attn_fwd(const bf16_t* __restrict__ qbf,
                         const float* __restrict__ kf, const float* __restrict__ vf,
                         bf16_t* __restrict__ aout) {
  __shared__ bf16_t Ks[64 * 128];
  __shared__ bf16_t Vt[128 * 64];
  __shared__ bf16_t Ps[4 * 16 * 64];
  const int t = threadIdx.x, w = t >> 6, lane = t & 63;
  const int fr = lane & 15, fq = lane >> 4;
  const int qt = 31 - (int)blockIdx.x;    // big-work-first
  const int bh = blockIdx.y;
  const int q0 = qt * 64;
  const size_t bh_off = (size_t)bh * SS * HD;
  const float scale = 0.08838834764831845f;

  // Q frags (A-operand): row = q0+w*16+fr, k(d) = fq*8 + ks*32
  bf16x8 qfr[4];
  {
    const bf16_t* qrow = qbf + bh_off + (size_t)(q0 + w * 16 + fr) * HD;
#pragma unroll
    for (int ks = 0; ks < 4; ++ks) qfr[ks] = *(const bf16x8*)(qrow + fq * 8 + ks * 32);
  }

  float mrow[4], lrow[4];
  f32x4 accO[8] = {};
#pragma unroll
  for (int r = 0; r < 4; ++r) { mrow[r] = -1e30f; lrow[r] = 0.f; }

  for (int kt = 0; kt <= qt; ++kt) {
    const int kv0 = kt * 64;
    __syncthreads();  // previous tile's LDS reads done
    // stage K (bf16 swz) and V^T (bf16 swz): 64x128 fp32 each, 8 float4/thread
#pragma unroll
    for (int j = 0; j < 8; ++j) {
      int idx = j * 256 + t;       // 0..2047 float4 units
      int rr = idx >> 5;           // kv row 0..63
      int c4 = idx & 31;           // float4 within row
      const size_t gofs = bh_off + (size_t)(kv0 + rr) * HD + c4 * 4;
      float4v kvv = *(const float4v*)(kf + gofs);
      ushort4v kp;
      kp.x = f2bf(kvv.x); kp.y = f2bf(kvv.y); kp.z = f2bf(kvv.z); kp.w = f2bf(kvv.w);
      int kb = rr * 256 + ((((c4 >> 1) ^ (rr & 7)) << 4) | ((c4 & 1) << 3));
      *(ushort4v*)((char*)Ks + kb) = kp;
      float4v vvv = *(const float4v*)(vf + gofs);
      unsigned short vp[4] = { f2bf(vvv.x), f2bf(vvv.y), f2bf(vvv.z), f2bf(vvv.w) };
#pragma unroll
      for (int qd = 0; qd < 4; ++qd) {
        int drow = c4 * 4 + qd;
        int sb = rr * 2;  // byte col in Vt row
        int vb = drow * 128 + ((((sb >> 4) ^ (drow & 7)) << 4) | (sb & 15));
        *(unsigned short*)((char*)Vt + vb) = vp[qd];
      }
    }
    __syncthreads();

    // QK^T: S[16 x 64] per wave
    f32x4 sfr[4] = {};
#pragma unroll
    for (int n = 0; n < 4; ++n) {
#pragma unroll
      for (int ks = 0; ks < 4; ++ks) {
        int row = n * 16 + fr;
        int chunk = (fq + ks * 4) ^ (row & 7);
        bf16x8 kfrag = *(const bf16x8*)((char*)Ks + row * 256 + chunk * 16);
        sfr[n] = __builtin_amdgcn_mfma_f32_16x16x32_bf16(qfr[ks], kfrag, sfr[n], 0, 0, 0);
      }
    }

    // mask + online softmax (rows = fq*4+r, cols = n*16+fr)
    float p[4][4], rmax[4];
    const bool diag = (kt == qt);
#pragma unroll
    for (int r = 0; r < 4; ++r) rmax[r] = -1e30f;
#pragma unroll
    for (int n = 0; n < 4; ++n) {
      int colg = kv0 + n * 16 + fr;
#pragma unroll
      for (int r = 0; r < 4; ++r) {
        float sv = sfr[n][r] * scale;
        int rowg = q0 + w * 16 + fq * 4 + r;
        if (diag && colg > rowg) sv = -1e30f;
        p[n][r] = sv;
        rmax[r] = fmaxf(rmax[r], sv);
      }
    }
#pragma unroll
    for (int r = 0; r < 4; ++r) {
#pragma unroll
      for (int md = 1; md < 16; md <<= 1)
        rmax[r] = fmaxf(rmax[r], __shfl_xor(rmax[r], md, 64));
    }
    float fct[4], rsum[4];
#pragma unroll
    for (int r = 0; r < 4; ++r) {
      float mnew = fmaxf(mrow[r], rmax[r]);
      fct[r] = __expf(mrow[r] - mnew);
      mrow[r] = mnew;
      float s0 = 0.f;
#pragma unroll
      for (int n = 0; n < 4; ++n) {
        float e = __expf(p[n][r] - mnew);
        p[n][r] = e;
        s0 += e;
      }
      rsum[r] = s0;
    }
#pragma unroll
    for (int r = 0; r < 4; ++r) {
#pragma unroll
      for (int md = 1; md < 16; md <<= 1)
        rsum[r] += __shfl_xor(rsum[r], md, 64);
      lrow[r] = lrow[r] * fct[r] + rsum[r];
    }
#pragma unroll
    for (int nf = 0; nf < 8; ++nf)
#pragma unroll
      for (int r = 0; r < 4; ++r) accO[nf][r] *= fct[r];

    // write P (bf16) to per-wave LDS [16][64], swizzled
    bf16_t* Pw = Ps + w * 1024;
#pragma unroll
    for (int n = 0; n < 4; ++n) {
#pragma unroll
      for (int r = 0; r < 4; ++r) {
        int prow = fq * 4 + r;
        int pcb = (n * 16 + fr) * 2;
        int pb = prow * 128 + ((((pcb >> 4) ^ (prow & 7)) << 4) | (pcb & 15));
        *(unsigned short*)((char*)Pw + pb) = f2bf(p[n][r]);
      }
    }
    __syncthreads();

    // PV: O[16 x 128] += P[16 x 64] * V[64 x 128]
#pragma unroll
    for (int ks = 0; ks < 2; ++ks) {
      int prow = fr;
      int pchunk = (fq + ks * 4) ^ (prow & 7);
      bf16x8 pfr = *(const bf16x8*)((char*)Pw + prow * 128 + pchunk * 16);
#pragma unroll
      for (int nf = 0; nf < 8; ++nf) {
        int vrow = nf * 16 + fr;
        int vchunk = (fq + ks * 4) ^ (vrow & 7);
        bf16x8 vfr = *(const bf16x8*)((char*)Vt + vrow * 128 + vchunk * 16);
        accO[nf] = __builtin_amdgcn_mfma_f32_16x16x32_bf16(pfr, vfr, accO[nf], 0, 0, 0);
      }
    }
  }

  // normalize + write attn out as [b, s, h*128+d] bf16
  const int b = bh >> 4, h = bh & 15;
#pragma unroll
  for (int r = 0; r < 4; ++r) {
    float inv = 1.0f / lrow[r];
    int srow = q0 + w * 16 + fq * 4 + r;
    bf16_t* orow = aout + ((size_t)(b * SS + srow)) * DM + h * HD;
#pragma unroll
    for (int nf = 0; nf < 8; ++nf)
      orow[nf * 16 + fr] = (bf16_t)(accO[nf][r] * inv);
  }
}

// ---------------- launch ---------------------------------------------------
extern "C" void kernel_launch(void* const* d_in, const int* in_sizes, int n_in,
                              void* d_out, int out_size, void* d_ws, size_t ws_size,
                              hipStream_t stream) {
  (void)in_sizes; (void)n_in; (void)out_size; (void)ws_size;
  const float* x  = (const float*)d_in[0];
  const float* Wq = (const float*)d_in[1];
  const float* Wk = (const float*)d_in[2];
  const float* Wv = (const float*)d_in[3];
  const float* Wo = (const float*)d_in[4];

  float* y  = (float*)d_out;                       // [8192, 2048]
  float* kf = y + (size_t)BS * DM;                 // [b,h,s,d]
  float* vf = kf + (size_t)BS * DM;

  char* ws = (char*)d_ws;
  bf16_t* xbf  = (bf16_t*)ws;                                      // 32MB (reused as attn out)
  bf16_t* wqkv = (bf16_t*)(ws + 33554432);                         // 24MB
  bf16_t* wobf = (bf16_t*)(ws + 33554432 + 25165824);              // 8MB
  bf16_t* qbf  = (bf16_t*)(ws + 33554432 + 25165824 + 8388608);    // 32MB
  bf16_t* abf  = xbf;

  conv_f32_bf16<<<2048, 256, 0, stream>>>(x, (unsigned short*)xbf, BS * DM / 4);
  conv_f32_bf16<<<512, 256, 0, stream>>>(Wq, (unsigned short*)wqkv, DM * DM / 4);
  conv_f32_bf16<<<512, 256, 0, stream>>>(Wk, (unsigned short*)(wqkv + (size_t)DM * DM), DM * DM / 4);
  conv_f32_bf16<<<512, 256, 0, stream>>>(Wv, (unsigned short*)(wqkv + 2 * (size_t)DM * DM), DM * DM / 4);
  conv_f32_bf16<<<512, 256, 0, stream>>>(Wo, (unsigned short*)wobf, DM * DM / 4);

  gemm_bt<1><<<dim3(BS / 128, NQKV / 128), 256, 0, stream>>>(
      xbf, wqkv, BS, NQKV, DM, nullptr, qbf, kf, vf);

  attn_fwd<<<dim3(32, 64), 256, 0, stream>>>(qbf, kf, vf, abf);

  gemm_bt<0><<<dim3(BS / 128, DM / 128), 256, 0, stream>>>(
      abf, wobf, BS, DM, DM, y, nullptr, nullptr, nullptr);
}

// Round 2
// 671.260 us; speedup vs baseline: 2.2945x; 2.2945x over previous
//
#include <hip/hip_runtime.h>
#include <stdint.h>

#define DM 2048
#define NH 16
#define HD 128
#define BB 4
#define SS 2048
#define BS (BB*SS)      // 8192 rows
#define NQKV (3*DM)     // 6144

typedef __bf16 bf16_t;
typedef __attribute__((ext_vector_type(8))) __bf16 bf16x8;
typedef __attribute__((ext_vector_type(4))) float f32x4;
typedef __attribute__((ext_vector_type(4))) float float4v;
typedef __attribute__((ext_vector_type(4))) unsigned int uint4v;
typedef __attribute__((ext_vector_type(4))) unsigned short ushort4v;
typedef __attribute__((ext_vector_type(8))) unsigned short ushort8;

__device__ __forceinline__ unsigned short f2bf(float f) {
  unsigned u = __float_as_uint(f);
  u += 0x7fffu + ((u >> 16) & 1u);
  return (unsigned short)(u >> 16);
}

// ---------------- fp32 -> bf16 conversion (vectorized, grid-stride) -------
__global__ void conv_f32_bf16(const float* __restrict__ in,
                              unsigned short* __restrict__ out, int n4) {
  int i = blockIdx.x * blockDim.x + threadIdx.x;
  int stride = gridDim.x * blockDim.x;
  for (; i < n4; i += stride) {
    float4v v = ((const float4v*)in)[i];
    ushort4v o;
    o.x = f2bf(v.x); o.y = f2bf(v.y); o.z = f2bf(v.z); o.w = f2bf(v.w);
    ((ushort4v*)out)[i] = o;
  }
}

// ---------------- GEMM C = A * B^T  (A [M,K] bf16, B [N,K] bf16) ----------
// 128x128 tile, 4 waves (2x2 of 64x64), BK=32, mfma 16x16x32 bf16.
template<int MODE>
__global__ void gemm_bt(const bf16_t* __restrict__ A, const bf16_t* __restrict__ Bm,
                        const int M, const int N, const int K,
                        float* __restrict__ Cf,
                        bf16_t* __restrict__ qbf,
                        float* __restrict__ kf, float* __restrict__ vf) {
  __shared__ bf16_t As[128 * 32];
  __shared__ bf16_t Bs[128 * 32];
  const int t = threadIdx.x;
  const int w = t >> 6, lane = t & 63;
  const int wm = (w >> 1) * 64, wn = (w & 1) * 64;
  const int row0 = blockIdx.x * 128, col0 = blockIdx.y * 128;
  const int fr = lane & 15, fq = lane >> 4;

  f32x4 acc[4][4] = {};

  for (int kk = 0; kk < K; kk += 32) {
#pragma unroll
    for (int j = 0; j < 2; ++j) {
      int idx = j * 256 + t;           // 16B-unit index 0..511
      int r = idx >> 2, c = idx & 3;   // row 0..127, 16B chunk 0..3
      uint4v dA = *(const uint4v*)(A + (size_t)(row0 + r) * K + kk + c * 8);
      uint4v dB = *(const uint4v*)(Bm + (size_t)(col0 + r) * K + kk + c * 8);
      int so = r * 32 + ((c ^ (r & 3)) * 8);
      *(uint4v*)(As + so) = dA;
      *(uint4v*)(Bs + so) = dB;
    }
    __syncthreads();
    bf16x8 af[4], bfv[4];
#pragma unroll
    for (int f = 0; f < 4; ++f) {
      int ra = wm + f * 16 + fr;
      af[f] = *(const bf16x8*)(As + ra * 32 + ((fq ^ (ra & 3)) * 8));
      int rb = wn + f * 16 + fr;
      bfv[f] = *(const bf16x8*)(Bs + rb * 32 + ((fq ^ (rb & 3)) * 8));
    }
#pragma unroll
    for (int i = 0; i < 4; ++i)
#pragma unroll
      for (int jn = 0; jn < 4; ++jn)
        acc[i][jn] = __builtin_amdgcn_mfma_f32_16x16x32_bf16(af[i], bfv[jn], acc[i][jn], 0, 0, 0);
    __syncthreads();
  }

#pragma unroll
  for (int i = 0; i < 4; ++i) {
#pragma unroll
    for (int jn = 0; jn < 4; ++jn) {
#pragma unroll
      for (int r = 0; r < 4; ++r) {
        int m = row0 + wm + i * 16 + fq * 4 + r;
        int n = col0 + wn + jn * 16 + fr;
        float v = acc[i][jn][r];
        if (MODE == 0) {
          Cf[(size_t)m * N + n] = v;
        } else {
          int b = m >> 11, s = m & 2047;
          if (n < DM) {
            int h = n >> 7, d = n & 127;
            qbf[(((size_t)(b * NH + h)) * SS + s) * HD + d] = (bf16_t)v;
          } else if (n < 2 * DM) {
            int nn = n - DM, h = nn >> 7, d = nn & 127;
            kf[(((size_t)(b * NH + h)) * SS + s) * HD + d] = v;
          } else {
            int nn = n - 2 * DM, h = nn >> 7, d = nn & 127;
            vf[(((size_t)(b * NH + h)) * SS + s) * HD + d] = v;
          }
        }
      }
    }
  }
}

// ---------------- V transpose: fp32 [bh][s][d] -> bf16 [bh][d][s] ----------
__global__ void vtrans(const float* __restrict__ vf, bf16_t* __restrict__ vt) {
  __shared__ unsigned short T[128 * 64];  // [d][s-chunk] swizzled, 16KB
  const int t = threadIdx.x;
  const int s0 = blockIdx.x * 64;
  const int bh = blockIdx.y;
  const size_t in_off = (size_t)bh * SS * HD;
  const int sr = t >> 5, c4 = t & 31;
#pragma unroll
  for (int j = 0; j < 8; ++j) {
    int s = j * 8 + sr;
    float4v v = *(const float4v*)(vf + in_off + (size_t)(s0 + s) * HD + c4 * 4);
#pragma unroll
    for (int q = 0; q < 4; ++q) {
      int d = c4 * 4 + q;
      int bc = s * 2;
      int byt = d * 128 + ((((bc >> 4) ^ (d & 7)) << 4) | (bc & 15));
      *(unsigned short*)((char*)T + byt) = f2bf(v[q]);
    }
  }
  __syncthreads();
  const int dr = t >> 3, c8 = t & 7;
  unsigned short* out = (unsigned short*)vt + (size_t)bh * HD * SS;
#pragma unroll
  for (int j = 0; j < 4; ++j) {
    int d = j * 32 + dr;
    ushort8 val = *(const ushort8*)((char*)T + d * 128 + ((c8 ^ (d & 7)) << 4));
    *(ushort8*)(out + (size_t)d * SS + s0 + c8 * 8) = val;
  }
}

// ---------------- causal flash attention v2 --------------------------------
// 1024 blocks (XCD-chunk swizzled), 256 thr = 4 waves. QB=128 (32 q-rows/wave),
// KVB=64. K staged fp32->bf16, V^T staged bf16, both double-buffered w/ XOR
// swizzle; one barrier per tile; async stage split (loads before barrier,
// LDS writes after softmax).
__global__ __launch_bounds__(256, 2)
void attn_fwd2(const bf16_t* __restrict__ qbf, const float* __restrict__ kf,
               const bf16_t* __restrict__ vt, bf16_t* __restrict__ aout) {
  __shared__ bf16_t Ks[2][64 * 128];
  __shared__ bf16_t Vs[2][128 * 64];
  __shared__ bf16_t Ps[4][32 * 64];
  const int t = threadIdx.x, w = t >> 6, lane = t & 63;
  const int fr = lane & 15, fq = lane >> 4;
  const int orig = blockIdx.x;
  const int wg = (orig & 7) * 128 + (orig >> 3);   // XCD-chunked, bijective
  const int bh = wg >> 4;
  const int qt = 15 - (wg & 15);                   // big-first within bh
  const int q0 = qt * 128;
  const size_t bh_off = (size_t)bh * SS * HD;
  const unsigned short* vtb = (const unsigned short*)vt + (size_t)bh * HD * SS;
  const float scale = 0.08838834764831845f;
  const int nt = 2 * qt + 2;

  // Q fragments: rows q0 + w*32 + u*16 + fr, k = fq*8 + ks*32
  bf16x8 qfr[2][4];
#pragma unroll
  for (int u = 0; u < 2; ++u) {
    const bf16_t* qrow = qbf + bh_off + (size_t)(q0 + w * 32 + u * 16 + fr) * HD;
#pragma unroll
    for (int ks = 0; ks < 4; ++ks) qfr[u][ks] = *(const bf16x8*)(qrow + fq * 8 + ks * 32);
  }

  const int kr = t >> 4, kc = t & 15;  // K stage: row j*16+kr, 16B chunk kc
  const int vr = t >> 3, vc = t & 7;   // V stage: row j*32+vr, 16B chunk vc

  float mrow[2][4], lrow[2][4];
  f32x4 accO[2][8] = {};
#pragma unroll
  for (int u = 0; u < 2; ++u)
#pragma unroll
    for (int r = 0; r < 4; ++r) { mrow[u][r] = -1e30f; lrow[u][r] = 0.f; }

  float4v kreg[8]; ushort8 vreg[4];
  // ---- prologue: load+write tile 0 ----
#pragma unroll
  for (int j = 0; j < 4; ++j) {
    const float* src = kf + bh_off + (size_t)(j * 16 + kr) * HD + kc * 8;
    kreg[2 * j] = *(const float4v*)src;
    kreg[2 * j + 1] = *(const float4v*)(src + 4);
    vreg[j] = *(const ushort8*)(vtb + (size_t)(j * 32 + vr) * SS + vc * 8);
  }
#pragma unroll
  for (int j = 0; j < 4; ++j) {
    int r = j * 16 + kr;
    ushort8 kp;
    kp[0] = f2bf(kreg[2*j].x);   kp[1] = f2bf(kreg[2*j].y);
    kp[2] = f2bf(kreg[2*j].z);   kp[3] = f2bf(kreg[2*j].w);
    kp[4] = f2bf(kreg[2*j+1].x); kp[5] = f2bf(kreg[2*j+1].y);
    kp[6] = f2bf(kreg[2*j+1].z); kp[7] = f2bf(kreg[2*j+1].w);
    *(ushort8*)((char*)Ks[0] + r * 256 + ((kc ^ (r & 7)) << 4)) = kp;
    int rd = j * 32 + vr;
    *(ushort8*)((char*)Vs[0] + rd * 128 + ((vc ^ (rd & 7)) << 4)) = vreg[j];
  }

  for (int kt = 0; kt < nt; ++kt) {
    const int cur = kt & 1;
    // ---- issue next tile's global loads (latency hides under QK^T+softmax)
    if (kt + 1 < nt) {
      const int kv0n = (kt + 1) * 64;
#pragma unroll
      for (int j = 0; j < 4; ++j) {
        const float* src = kf + bh_off + (size_t)(kv0n + j * 16 + kr) * HD + kc * 8;
        kreg[2 * j] = *(const float4v*)src;
        kreg[2 * j + 1] = *(const float4v*)(src + 4);
        vreg[j] = *(const ushort8*)(vtb + (size_t)(j * 32 + vr) * SS + kv0n + vc * 8);
      }
    }
    __syncthreads();   // buf[cur] writes (prev iter) visible to all waves

    // ---- QK^T: S[32 x 64] per wave (2 row-frags share each K-frag)
    f32x4 sfr[2][4] = {};
#pragma unroll
    for (int n = 0; n < 4; ++n) {
      int row = n * 16 + fr;
#pragma unroll
      for (int ks = 0; ks < 4; ++ks) {
        bf16x8 kfrag = *(const bf16x8*)((char*)Ks[cur] + row * 256 + (((fq + ks * 4) ^ (row & 7)) << 4));
        sfr[0][n] = __builtin_amdgcn_mfma_f32_16x16x32_bf16(qfr[0][ks], kfrag, sfr[0][n], 0, 0, 0);
        sfr[1][n] = __builtin_amdgcn_mfma_f32_16x16x32_bf16(qfr[1][ks], kfrag, sfr[1][n], 0, 0, 0);
      }
    }

    // ---- online softmax (rows u*16+fq*4+r, cols n*16+fr) + P write
    const int kv0 = kt * 64;
    const bool needmask = (kt >= 2 * qt);
    bf16_t* Pw = Ps[w];
#pragma unroll
    for (int u = 0; u < 2; ++u) {
      float pv[4][4], rmax[4];
#pragma unroll
      for (int r = 0; r < 4; ++r) rmax[r] = -1e30f;
#pragma unroll
      for (int n = 0; n < 4; ++n) {
        int colg = kv0 + n * 16 + fr;
#pragma unroll
        for (int r = 0; r < 4; ++r) {
          float sv = sfr[u][n][r] * scale;
          if (needmask) {
            int rowg = q0 + w * 32 + u * 16 + fq * 4 + r;
            if (colg > rowg) sv = -1e30f;
          }
          pv[n][r] = sv;
          rmax[r] = fmaxf(rmax[r], sv);
        }
      }
#pragma unroll
      for (int r = 0; r < 4; ++r) {
#pragma unroll
        for (int md = 1; md < 16; md <<= 1)
          rmax[r] = fmaxf(rmax[r], __shfl_xor(rmax[r], md, 64));
      }
#pragma unroll
      for (int r = 0; r < 4; ++r) {
        float mnew = fmaxf(mrow[u][r], rmax[r]);
        float fct = __expf(mrow[u][r] - mnew);
        mrow[u][r] = mnew;
        float s0 = 0.f;
#pragma unroll
        for (int n = 0; n < 4; ++n) {
          float e = __expf(pv[n][r] - mnew);
          pv[n][r] = e;
          s0 += e;
        }
#pragma unroll
        for (int md = 1; md < 16; md <<= 1) s0 += __shfl_xor(s0, md, 64);
        lrow[u][r] = lrow[u][r] * fct + s0;
#pragma unroll
        for (int nf = 0; nf < 8; ++nf) accO[u][nf][r] *= fct;
        int prow = u * 16 + fq * 4 + r;
#pragma unroll
        for (int n = 0; n < 4; ++n) {
          int bc = (n * 16 + fr) * 2;
          int byt = prow * 128 + ((((bc >> 4) ^ (prow & 7)) << 4) | (bc & 15));
          *(unsigned short*)((char*)Pw + byt) = f2bf(pv[n][r]);
        }
      }
    }

    // ---- write next tile into buf[cur^1] (vmcnt waits inserted by compiler)
    if (kt + 1 < nt) {
#pragma unroll
      for (int j = 0; j < 4; ++j) {
        int r = j * 16 + kr;
        ushort8 kp;
        kp[0] = f2bf(kreg[2*j].x);   kp[1] = f2bf(kreg[2*j].y);
        kp[2] = f2bf(kreg[2*j].z);   kp[3] = f2bf(kreg[2*j].w);
        kp[4] = f2bf(kreg[2*j+1].x); kp[5] = f2bf(kreg[2*j+1].y);
        kp[6] = f2bf(kreg[2*j+1].z); kp[7] = f2bf(kreg[2*j+1].w);
        *(ushort8*)((char*)Ks[cur ^ 1] + r * 256 + ((kc ^ (r & 7)) << 4)) = kp;
        int rd = j * 32 + vr;
        *(ushort8*)((char*)Vs[cur ^ 1] + rd * 128 + ((vc ^ (rd & 7)) << 4)) = vreg[j];
      }
    }

    // ---- PV: O[32 x 128] += P[32 x 64] * V[64 x 128]
#pragma unroll
    for (int ks = 0; ks < 2; ++ks) {
      bf16x8 pfr[2];
#pragma unroll
      for (int u = 0; u < 2; ++u) {
        int prow = u * 16 + fr;
        pfr[u] = *(const bf16x8*)((char*)Pw + prow * 128 + (((fq + ks * 4) ^ (prow & 7)) << 4));
      }
#pragma unroll
      for (int nf = 0; nf < 8; ++nf) {
        int vrow = nf * 16 + fr;
        bf16x8 vfrag = *(const bf16x8*)((char*)Vs[cur] + vrow * 128 + (((fq + ks * 4) ^ (vrow & 7)) << 4));
        accO[0][nf] = __builtin_amdgcn_mfma_f32_16x16x32_bf16(pfr[0], vfrag, accO[0][nf], 0, 0, 0);
        accO[1][nf] = __builtin_amdgcn_mfma_f32_16x16x32_bf16(pfr[1], vfrag, accO[1][nf], 0, 0, 0);
      }
    }
  }

  // ---- normalize + write attn out as [b, s, h*128+d] bf16
  const int b = bh >> 4, h = bh & 15;
#pragma unroll
  for (int u = 0; u < 2; ++u) {
#pragma unroll
    for (int r = 0; r < 4; ++r) {
      float inv = 1.0f / lrow[u][r];
      int srow = q0 + w * 32 + u * 16 + fq * 4 + r;
      bf16_t* orow = aout + ((size_t)(b * SS + srow)) * DM + h * HD;
#pragma unroll
      for (int nf = 0; nf < 8; ++nf)
        orow[nf * 16 + fr] = (bf16_t)(accO[u][nf][r] * inv);
    }
  }
}

// ---------------- launch ---------------------------------------------------
extern "C" void kernel_launch(void* const* d_in, const int* in_sizes, int n_in,
                              void* d_out, int out_size, void* d_ws, size_t ws_size,
                              hipStream_t stream) {
  (void)in_sizes; (void)n_in; (void)out_size; (void)ws_size;
  const float* x  = (const float*)d_in[0];
  const float* Wq = (const float*)d_in[1];
  const float* Wk = (const float*)d_in[2];
  const float* Wv = (const float*)d_in[3];
  const float* Wo = (const float*)d_in[4];

  float* y  = (float*)d_out;                       // [8192, 2048]
  float* kf = y + (size_t)BS * DM;                 // fp32 [b,h,s,d]
  float* vf = kf + (size_t)BS * DM;

  // ws layout (96MB total, all reuse time-disjoint on the serial stream):
  //  [0,32M)  xbf (conv->QKVgemm), then abf (attn out -> out-proj)
  //  [32,64M) qbf (gemm->attn), then wobf (conv after attn -> out-proj)
  //  [64,88M) wqkv (conv->QKVgemm); [64,96M) vtb (vtrans after gemm -> attn)
  char* ws = (char*)d_ws;
  bf16_t* xbf  = (bf16_t*)ws;
  bf16_t* abf  = xbf;
  bf16_t* qbf  = (bf16_t*)(ws + (size_t)32 * 1024 * 1024);
  bf16_t* wobf = qbf;
  bf16_t* wqkv = (bf16_t*)(ws + (size_t)64 * 1024 * 1024);
  bf16_t* vtb  = wqkv;

  conv_f32_bf16<<<2048, 256, 0, stream>>>(x, (unsigned short*)xbf, BS * DM / 4);
  conv_f32_bf16<<<512, 256, 0, stream>>>(Wq, (unsigned short*)wqkv, DM * DM / 4);
  conv_f32_bf16<<<512, 256, 0, stream>>>(Wk, (unsigned short*)(wqkv + (size_t)DM * DM), DM * DM / 4);
  conv_f32_bf16<<<512, 256, 0, stream>>>(Wv, (unsigned short*)(wqkv + 2 * (size_t)DM * DM), DM * DM / 4);

  gemm_bt<1><<<dim3(BS / 128, NQKV / 128), 256, 0, stream>>>(
      xbf, wqkv, BS, NQKV, DM, nullptr, qbf, kf, vf);

  vtrans<<<dim3(SS / 64, BB * NH), 256, 0, stream>>>(vf, vtb);

  attn_fwd2<<<1024, 256, 0, stream>>>(qbf, kf, vtb, abf);

  conv_f32_bf16<<<512, 256, 0, stream>>>(Wo, (unsigned short*)wobf, DM * DM / 4);

  gemm_bt<0><<<dim3(BS / 128, DM / 128), 256, 0, stream>>>(
      abf, wobf, BS, DM, DM, y, nullptr, nullptr, nullptr);
}

// Round 4
// 531.683 us; speedup vs baseline: 2.8968x; 1.2625x over previous
//
#include <hip/hip_runtime.h>
#include <stdint.h>

#define DM 2048
#define NH 16
#define HD 128
#define BB 4
#define SS 2048
#define BS (BB*SS)      // 8192 rows
#define NQKV (3*DM)     // 6144
// softmax scale folded into Q at GEMM epilogue, in exp2 domain:
// 1/sqrt(128) * log2(e)
#define SCQ 0.12751744565f

typedef __bf16 bf16_t;
typedef __attribute__((ext_vector_type(8))) __bf16 bf16x8;
typedef __attribute__((ext_vector_type(4))) float f32x4;
typedef __attribute__((ext_vector_type(16))) float f32x16;
typedef __attribute__((ext_vector_type(4))) float float4v;
typedef __attribute__((ext_vector_type(4))) unsigned int uint4v;
typedef __attribute__((ext_vector_type(4))) unsigned short ushort4v;
typedef __attribute__((ext_vector_type(8))) unsigned short ushort8;

__device__ __forceinline__ unsigned short f2bf(float f) {
  unsigned u = __float_as_uint(f);
  u += 0x7fffu + ((u >> 16) & 1u);
  return (unsigned short)(u >> 16);
}

// async global->LDS, 16B per lane; dest = (wave-uniform) l + lane*16
__device__ __forceinline__ void gl16(const void* g, void* l) {
  __builtin_amdgcn_global_load_lds(
      (const __attribute__((address_space(1))) unsigned int*)(unsigned long long)g,
      (__attribute__((address_space(3))) unsigned int*)(unsigned int)(unsigned long long)l,
      16, 0, 0);
}

// ---------------- fp32 -> bf16 conversion (vectorized, grid-stride) -------
__global__ void conv_f32_bf16(const float* __restrict__ in,
                              unsigned short* __restrict__ out, int n4) {
  int i = blockIdx.x * blockDim.x + threadIdx.x;
  int stride = gridDim.x * blockDim.x;
  for (; i < n4; i += stride) {
    float4v v = ((const float4v*)in)[i];
    ushort4v o;
    o.x = f2bf(v.x); o.y = f2bf(v.y); o.z = f2bf(v.z); o.w = f2bf(v.w);
    ((ushort4v*)out)[i] = o;
  }
}

// ---------------- bf16 -> fp32 expand (for k output) ----------------------
__global__ void conv_bf16_f32(const unsigned short* __restrict__ in,
                              float* __restrict__ out, int n4) {
  int i = blockIdx.x * blockDim.x + threadIdx.x;
  int stride = gridDim.x * blockDim.x;
  for (; i < n4; i += stride) {
    ushort4v v = ((const ushort4v*)in)[i];
    float4v o;
    o.x = __uint_as_float((unsigned)v.x << 16);
    o.y = __uint_as_float((unsigned)v.y << 16);
    o.z = __uint_as_float((unsigned)v.z << 16);
    o.w = __uint_as_float((unsigned)v.w << 16);
    ((float4v*)out)[i] = o;
  }
}

// ---------------- GEMM C = A * B^T  (A [M,K] bf16, B [N,K] bf16) ----------
// 128x128 tile, 4 waves (2x2 of 64x64), BK=32, mfma 16x16x32 bf16.
// MODE 0: C -> fp32 row-major [M,N]
// MODE 1: QKV scatter: q bf16*SCQ [b,h,s,d]; k bf16 [b,h,s,d]; v fp32 [b,h,s,d]
template<int MODE>
__global__ void gemm_bt(const bf16_t* __restrict__ A, const bf16_t* __restrict__ Bm,
                        const int M, const int N, const int K,
                        float* __restrict__ Cf,
                        bf16_t* __restrict__ qbf,
                        bf16_t* __restrict__ kbt, float* __restrict__ vf) {
  __shared__ bf16_t As[128 * 32];
  __shared__ bf16_t Bs[128 * 32];
  const int t = threadIdx.x;
  const int w = t >> 6, lane = t & 63;
  const int wm = (w >> 1) * 64, wn = (w & 1) * 64;
  const int row0 = blockIdx.x * 128, col0 = blockIdx.y * 128;
  const int fr = lane & 15, fq = lane >> 4;

  f32x4 acc[4][4] = {};

  for (int kk = 0; kk < K; kk += 32) {
#pragma unroll
    for (int j = 0; j < 2; ++j) {
      int idx = j * 256 + t;           // 16B-unit index 0..511
      int r = idx >> 2, c = idx & 3;   // row 0..127, 16B chunk 0..3
      uint4v dA = *(const uint4v*)(A + (size_t)(row0 + r) * K + kk + c * 8);
      uint4v dB = *(const uint4v*)(Bm + (size_t)(col0 + r) * K + kk + c * 8);
      int so = r * 32 + ((c ^ (r & 3)) * 8);
      *(uint4v*)(As + so) = dA;
      *(uint4v*)(Bs + so) = dB;
    }
    __syncthreads();
    bf16x8 af[4], bfv[4];
#pragma unroll
    for (int f = 0; f < 4; ++f) {
      int ra = wm + f * 16 + fr;
      af[f] = *(const bf16x8*)(As + ra * 32 + ((fq ^ (ra & 3)) * 8));
      int rb = wn + f * 16 + fr;
      bfv[f] = *(const bf16x8*)(Bs + rb * 32 + ((fq ^ (rb & 3)) * 8));
    }
#pragma unroll
    for (int i = 0; i < 4; ++i)
#pragma unroll
      for (int jn = 0; jn < 4; ++jn)
        acc[i][jn] = __builtin_amdgcn_mfma_f32_16x16x32_bf16(af[i], bfv[jn], acc[i][jn], 0, 0, 0);
    __syncthreads();
  }

#pragma unroll
  for (int i = 0; i < 4; ++i) {
#pragma unroll
    for (int jn = 0; jn < 4; ++jn) {
#pragma unroll
      for (int r = 0; r < 4; ++r) {
        int m = row0 + wm + i * 16 + fq * 4 + r;
        int n = col0 + wn + jn * 16 + fr;
        float v = acc[i][jn][r];
        if (MODE == 0) {
          Cf[(size_t)m * N + n] = v;
        } else {
          int b = m >> 11, s = m & 2047;
          if (n < DM) {
            int h = n >> 7, d = n & 127;
            qbf[(((size_t)(b * NH + h)) * SS + s) * HD + d] = (bf16_t)(v * SCQ);
          } else if (n < 2 * DM) {
            int nn = n - DM, h = nn >> 7, d = nn & 127;
            kbt[(((size_t)(b * NH + h)) * SS + s) * HD + d] = (bf16_t)v;
          } else {
            int nn = n - 2 * DM, h = nn >> 7, d = nn & 127;
            vf[(((size_t)(b * NH + h)) * SS + s) * HD + d] = v;
          }
        }
      }
    }
  }
}

// ---------------- V transpose: fp32 [bh][s][d] -> bf16 [bh][d][s] ----------
__global__ void vtrans(const float* __restrict__ vf, bf16_t* __restrict__ vt) {
  __shared__ unsigned short T[128 * 64];  // [d][s-chunk] swizzled, 16KB
  const int t = threadIdx.x;
  const int s0 = blockIdx.x * 64;
  const int bh = blockIdx.y;
  const size_t in_off = (size_t)bh * SS * HD;
  const int sr = t >> 5, c4 = t & 31;
#pragma unroll
  for (int j = 0; j < 8; ++j) {
    int s = j * 8 + sr;
    float4v v = *(const float4v*)(vf + in_off + (size_t)(s0 + s) * HD + c4 * 4);
#pragma unroll
    for (int q = 0; q < 4; ++q) {
      int d = c4 * 4 + q;
      int bc = s * 2;
      int byt = d * 128 + ((((bc >> 4) ^ (d & 7)) << 4) | (bc & 15));
      *(unsigned short*)((char*)T + byt) = f2bf(v[q]);
    }
  }
  __syncthreads();
  const int dr = t >> 3, c8 = t & 7;
  unsigned short* out = (unsigned short*)vt + (size_t)bh * HD * SS;
#pragma unroll
  for (int j = 0; j < 4; ++j) {
    int d = j * 32 + dr;
    ushort8 val = *(const ushort8*)((char*)T + d * 128 + ((c8 ^ (d & 7)) << 4));
    *(ushort8*)(out + (size_t)d * SS + s0 + c8 * 8) = val;
  }
}

// ---------------- causal flash attention v4 --------------------------------
// 1024 blocks (XCD-chunked), 256 thr = 4 waves. QB=128 (32 q/wave, 32x32 mfma),
// KVB=64. Swapped QK^T (P lane-local); P->A-frag rebuilt in-register via
// cvt_pk + shfl_xor(32) half-exchange (convention-safe). K/V^T staged bf16 via
// global_load_lds (per-lane inverse-swizzled source), double-buffered;
// pipeline: barrier -> issue next-tile gl16 -> compute cur (T3 2-phase).
__global__ __launch_bounds__(256, 2)
void attn_fwd4(const bf16_t* __restrict__ qbf, const bf16_t* __restrict__ kbf,
               const bf16_t* __restrict__ vt, bf16_t* __restrict__ aout) {
  __shared__ bf16_t Ks[2][64 * 128];   // [row s][256B = 16 chunks], chunk ^= (row&15)
  __shared__ bf16_t Vs[2][64 * 128];   // row R: d = 2R + (c>>3), k8 = c&7; chunk ^= (R&15)
  const int t = threadIdx.x, w = t >> 6, lane = t & 63;
  const int l31 = lane & 31, hi = lane >> 5;
  const int orig = blockIdx.x;
  const int wg = (orig & 7) * 128 + (orig >> 3);   // XCD-chunked, bijective (1024%8==0)
  const int bh = wg >> 4;
  const int qt = 15 - (wg & 15);                   // big-first within each XCD chunk
  const int q0 = qt * 128;
  const int nt = 2 * qt + 2;
  const size_t bh_off = (size_t)bh * SS * HD;
  const char* kbase = (const char*)(kbf + bh_off);
  const char* vbase = (const char*)(vt + bh_off);

  // per-lane staging sources (inverse-swizzled so linear LDS dest => swizzled tile)
  const char* ksrc[4];
  const char* vsrc[4];
#pragma unroll
  for (int i = 0; i < 4; ++i) {
    int r = (w * 4 + i) * 4 + (lane >> 4);
    int c = (lane & 15) ^ (r & 15);
    ksrc[i] = kbase + r * 256 + c * 16;
    int d = 2 * r + (c >> 3);
    vsrc[i] = vbase + (size_t)d * (SS * 2) + (c & 7) * 16;
  }

  // Q fragments (B-operand): col q = q0+w*32+l31, k(d) = ds*16 + hi*8 + e
  bf16x8 qfr[8];
  {
    const char* qrow = (const char*)(qbf + bh_off + (size_t)(q0 + w * 32 + l31) * HD);
#pragma unroll
    for (int ds = 0; ds < 8; ++ds)
      qfr[ds] = *(const bf16x8*)(qrow + ds * 32 + hi * 16);
  }

  // prologue: stage tile 0 into buf 0
#pragma unroll
  for (int i = 0; i < 4; ++i) {
    gl16(ksrc[i], (char*)(&Ks[0][0]) + (w * 4 + i) * 1024);
    gl16(vsrc[i], (char*)(&Vs[0][0]) + (w * 4 + i) * 1024);
    ksrc[i] += 16384;   // +64 kv rows * 256B
    vsrc[i] += 128;     // +64 kv cols * 2B
  }

  float mrow = -3.0e38f, lrow = 0.f;
  f32x16 accO[4] = {};   // O[q=(r&3)+8*(r>>2)+4hi][d=dt*32+l31]

  // In-reg P->A-frag. Lane owns P^T[crow(r,hi)][q=l31]; A-frag needs
  // P[q=l31][k=slot*16+hi*8+e]. Per 4-word group {A,B,C,D}=W[4g..4g+3]:
  //   word0 = hi ? xC : A ; word1 = hi ? xD : B
  //   word2 = hi ? C : xA ; word3 = hi ? D : xB     (x = shfl_xor 32)
  auto make_pa = [&](const f32x16& sv, bf16x8& paA, bf16x8& paB) {
    unsigned W[8];
#pragma unroll
    for (int m = 0; m < 8; ++m) {
      float lo = sv[2 * m], hh = sv[2 * m + 1];
      asm("v_cvt_pk_bf16_f32 %0, %1, %2" : "=v"(W[m]) : "v"(lo), "v"(hh));
    }
#pragma unroll
    for (int g = 0; g < 2; ++g) {
      unsigned A = W[4 * g], B = W[4 * g + 1], C = W[4 * g + 2], D = W[4 * g + 3];
      unsigned xA = (unsigned)__shfl_xor((int)A, 32, 64);
      unsigned xB = (unsigned)__shfl_xor((int)B, 32, 64);
      unsigned xC = (unsigned)__shfl_xor((int)C, 32, 64);
      unsigned xD = (unsigned)__shfl_xor((int)D, 32, 64);
      uint4v u;
      u.x = hi ? xC : A;
      u.y = hi ? xD : B;
      u.z = hi ? C : xA;
      u.w = hi ? D : xB;
      if (g == 0) paA = __builtin_bit_cast(bf16x8, u);
      else        paB = __builtin_bit_cast(bf16x8, u);
    }
  };

  for (int kt = 0; kt < nt; ++kt) {
    const int cur = kt & 1;
    __syncthreads();   // vmcnt(0) drain: tile kt staged; prev readers of buf[cur^1] done

    // ---- issue next tile's gl16 into buf[cur^1]; latency hides under compute
    if (kt + 1 < nt) {
#pragma unroll
      for (int i = 0; i < 4; ++i) {
        gl16(ksrc[i], (char*)(&Ks[cur ^ 1][0]) + (w * 4 + i) * 1024);
        gl16(vsrc[i], (char*)(&Vs[cur ^ 1][0]) + (w * 4 + i) * 1024);
        ksrc[i] += 16384;
        vsrc[i] += 128;
      }
    }

    // ---- swapped QK^T: S^T[k][q] per 32-k block (kb=0: s0, kb=1: s1)
    const char* kl = (const char*)&Ks[cur][0];
    f32x16 s0 = {}, s1 = {};
    const int rck = l31 & 15;   // (row & 15) same for rows l31 and 32+l31
    __builtin_amdgcn_s_setprio(1);
#pragma unroll
    for (int ds = 0; ds < 8; ++ds) {
      int ch = ((2 * ds + hi) ^ rck) << 4;
      bf16x8 kf0 = *(const bf16x8*)(kl + l31 * 256 + ch);
      s0 = __builtin_amdgcn_mfma_f32_32x32x16_bf16(kf0, qfr[ds], s0, 0, 0, 0);
      bf16x8 kf1 = *(const bf16x8*)(kl + (32 + l31) * 256 + ch);
      s1 = __builtin_amdgcn_mfma_f32_32x32x16_bf16(kf1, qfr[ds], s1, 0, 0, 0);
    }
    __builtin_amdgcn_s_setprio(0);

    // ---- mask (diag tiles) + online softmax in exp2 domain
    const int kv0 = kt * 64;
    if (kt >= 2 * qt) {
      const int qg = q0 + w * 32 + l31;
#pragma unroll
      for (int r = 0; r < 16; ++r) {
        int klo = kv0 + (r & 3) + 8 * (r >> 2) + 4 * hi;
        if (klo > qg) s0[r] = -3.0e38f;
        if (klo + 32 > qg) s1[r] = -3.0e38f;
      }
    }
    float rm = s0[0];
#pragma unroll
    for (int r = 1; r < 16; ++r) rm = fmaxf(rm, s0[r]);
#pragma unroll
    for (int r = 0; r < 16; ++r) rm = fmaxf(rm, s1[r]);
    rm = fmaxf(rm, __shfl_xor(rm, 32, 64));
    if (__ballot(rm > mrow + 8.0f)) {       // defer-max: rescale only on real growth
      float mnew = fmaxf(mrow, rm);
      float fct = __builtin_amdgcn_exp2f(mrow - mnew);
      mrow = mnew;
      lrow *= fct;
#pragma unroll
      for (int r = 0; r < 16; ++r) {
        float f = __shfl(fct, (r & 3) + 8 * (r >> 2) + 4 * hi, 64);
        accO[0][r] *= f; accO[1][r] *= f; accO[2][r] *= f; accO[3][r] *= f;
      }
    }
    float ss = 0.f;
#pragma unroll
    for (int r = 0; r < 16; ++r) { float p = __builtin_amdgcn_exp2f(s0[r] - mrow); s0[r] = p; ss += p; }
#pragma unroll
    for (int r = 0; r < 16; ++r) { float p = __builtin_amdgcn_exp2f(s1[r] - mrow); s1[r] = p; ss += p; }
    ss += __shfl_xor(ss, 32, 64);
    lrow += ss;

    // ---- P -> PV A-fragments (in-register, no LDS round trip)
    bf16x8 pa00, pa01, pa10, pa11;
    make_pa(s0, pa00, pa01);   // k slots 0,1 (k=0..31)
    make_pa(s1, pa10, pa11);   // k slots 2,3 (k=32..63)

    // ---- PV: O[32q x 128d] += P[32q x 64k] * V[64k x 128d]
    const char* vl = (const char*)&Vs[cur][0];
    __builtin_amdgcn_s_setprio(1);
#pragma unroll
    for (int dt = 0; dt < 4; ++dt) {
      int R = dt * 16 + (l31 >> 1);
      int cb = (l31 & 1) << 3;      // d-half*8
      int rx = R & 15;
      bf16x8 v00 = *(const bf16x8*)(vl + R * 256 + (((cb + 0 + hi) ^ rx) << 4));
      accO[dt] = __builtin_amdgcn_mfma_f32_32x32x16_bf16(pa00, v00, accO[dt], 0, 0, 0);
      bf16x8 v01 = *(const bf16x8*)(vl + R * 256 + (((cb + 2 + hi) ^ rx) << 4));
      accO[dt] = __builtin_amdgcn_mfma_f32_32x32x16_bf16(pa01, v01, accO[dt], 0, 0, 0);
      bf16x8 v10 = *(const bf16x8*)(vl + R * 256 + (((cb + 4 + hi) ^ rx) << 4));
      accO[dt] = __builtin_amdgcn_mfma_f32_32x32x16_bf16(pa10, v10, accO[dt], 0, 0, 0);
      bf16x8 v11 = *(const bf16x8*)(vl + R * 256 + (((cb + 6 + hi) ^ rx) << 4));
      accO[dt] = __builtin_amdgcn_mfma_f32_32x32x16_bf16(pa11, v11, accO[dt], 0, 0, 0);
    }
    __builtin_amdgcn_s_setprio(0);
  }

  // ---- normalize + write attn out as [b, s, h*128+d] bf16
  const int b = bh >> 4, h = bh & 15;
#pragma unroll
  for (int r = 0; r < 16; ++r) {
    int qr = (r & 3) + 8 * (r >> 2) + 4 * hi;
    float inv = __builtin_amdgcn_rcpf(__shfl(lrow, qr, 64));
    int srow = q0 + w * 32 + qr;
    bf16_t* orow = aout + ((size_t)(b * SS + srow)) * DM + h * HD + l31;
    orow[0]  = (bf16_t)(accO[0][r] * inv);
    orow[32] = (bf16_t)(accO[1][r] * inv);
    orow[64] = (bf16_t)(accO[2][r] * inv);
    orow[96] = (bf16_t)(accO[3][r] * inv);
  }
}

// ---------------- launch ---------------------------------------------------
extern "C" void kernel_launch(void* const* d_in, const int* in_sizes, int n_in,
                              void* d_out, int out_size, void* d_ws, size_t ws_size,
                              hipStream_t stream) {
  (void)in_sizes; (void)n_in; (void)out_size; (void)ws_size;
  const float* x  = (const float*)d_in[0];
  const float* Wq = (const float*)d_in[1];
  const float* Wk = (const float*)d_in[2];
  const float* Wv = (const float*)d_in[3];
  const float* Wo = (const float*)d_in[4];

  float* y  = (float*)d_out;                       // [8192, 2048] fp32
  float* kf = y + (size_t)BS * DM;                 // fp32 [b,h,s,d] (output)
  float* vf = kf + (size_t)BS * DM;                // fp32 [b,h,s,d] (output)

  // ws (max 96MB live):
  //  [0,32M)  xbf (conv->gemm1), then abf (attn out -> out-proj)
  //  [32,64M) qbf (gemm1->attn), then wobf (after attn -> out-proj)
  //  [64,88M) wqkv (conv->gemm1); [64,96M) vtb (vtrans -> attn)
  // y-region of d_out doubles as bf16 K [b,h,s,d] (gemm1->attn; y written last)
  char* ws = (char*)d_ws;
  bf16_t* xbf  = (bf16_t*)ws;
  bf16_t* abf  = xbf;
  bf16_t* qbf  = (bf16_t*)(ws + (size_t)32 * 1024 * 1024);
  bf16_t* wobf = qbf;
  bf16_t* wqkv = (bf16_t*)(ws + (size_t)64 * 1024 * 1024);
  bf16_t* vtb  = wqkv;
  bf16_t* kbt  = (bf16_t*)y;

  conv_f32_bf16<<<2048, 256, 0, stream>>>(x, (unsigned short*)xbf, BS * DM / 4);
  conv_f32_bf16<<<512, 256, 0, stream>>>(Wq, (unsigned short*)wqkv, DM * DM / 4);
  conv_f32_bf16<<<512, 256, 0, stream>>>(Wk, (unsigned short*)(wqkv + (size_t)DM * DM), DM * DM / 4);
  conv_f32_bf16<<<512, 256, 0, stream>>>(Wv, (unsigned short*)(wqkv + 2 * (size_t)DM * DM), DM * DM / 4);

  gemm_bt<1><<<dim3(BS / 128, NQKV / 128), 256, 0, stream>>>(
      xbf, wqkv, BS, NQKV, DM, nullptr, qbf, kbt, vf);

  conv_bf16_f32<<<2048, 256, 0, stream>>>((const unsigned short*)kbt, kf, BS * DM / 4);

  vtrans<<<dim3(SS / 64, BB * NH), 256, 0, stream>>>(vf, vtb);

  attn_fwd4<<<1024, 256, 0, stream>>>(qbf, kbt, vtb, abf);

  conv_f32_bf16<<<512, 256, 0, stream>>>(Wo, (unsigned short*)wobf, DM * DM / 4);

  gemm_bt<0><<<dim3(BS / 128, DM / 128), 256, 0, stream>>>(
      abf, wobf, BS, DM, DM, y, nullptr, nullptr, nullptr);
}

// Round 5
// 529.318 us; speedup vs baseline: 2.9098x; 1.0045x over previous
//
#include <hip/hip_runtime.h>
#include <stdint.h>

#define DM 2048
#define NH 16
#define HD 128
#define BB 4
#define SS 2048
#define BS (BB*SS)      // 8192 rows
#define NQKV (3*DM)     // 6144
// softmax scale folded into Q at GEMM epilogue, in exp2 domain:
// 1/sqrt(128) * log2(e)
#define SCQ 0.12751744565f

typedef __bf16 bf16_t;
typedef __attribute__((ext_vector_type(8))) __bf16 bf16x8;
typedef __attribute__((ext_vector_type(4))) float f32x4;
typedef __attribute__((ext_vector_type(16))) float f32x16;
typedef __attribute__((ext_vector_type(4))) float float4v;
typedef __attribute__((ext_vector_type(4))) unsigned int uint4v;
typedef __attribute__((ext_vector_type(4))) unsigned short ushort4v;
typedef __attribute__((ext_vector_type(8))) unsigned short ushort8;

__device__ __forceinline__ unsigned short f2bf(float f) {
  unsigned u = __float_as_uint(f);
  u += 0x7fffu + ((u >> 16) & 1u);
  return (unsigned short)(u >> 16);
}

// async global->LDS, 16B per lane; dest = (wave-uniform) l + lane*16
__device__ __forceinline__ void gl16(const void* g, void* l) {
  __builtin_amdgcn_global_load_lds(
      (const __attribute__((address_space(1))) unsigned int*)(unsigned long long)g,
      (__attribute__((address_space(3))) unsigned int*)(unsigned int)(unsigned long long)l,
      16, 0, 0);
}

// ---------------- fp32 -> bf16 conversion (vectorized, grid-stride) -------
__global__ void conv_f32_bf16(const float* __restrict__ in,
                              unsigned short* __restrict__ out, int n4) {
  int i = blockIdx.x * blockDim.x + threadIdx.x;
  int stride = gridDim.x * blockDim.x;
  for (; i < n4; i += stride) {
    float4v v = ((const float4v*)in)[i];
    ushort4v o;
    o.x = f2bf(v.x); o.y = f2bf(v.y); o.z = f2bf(v.z); o.w = f2bf(v.w);
    ((ushort4v*)out)[i] = o;
  }
}

// ---------------- GEMM C = A * B^T, 256x256 tile, ring-4 counted-vmcnt ----
// 512 thr = 8 waves (2M x 4N), per-wave 128x64, BK=32, mfma 16x16x32 bf16.
// LDS: 4 K-tile slots per matrix (16KB each), staged 3 tiles ahead via
// global_load_lds w16; s_waitcnt vmcnt(12) at tile top (never 0 mid-loop).
// Swizzle: 16B chunk c ^= (row>>1)&3, inverse on source / forward on read.
// MODE 0: C -> fp32 row-major [M,N]
// MODE 1: QKV scatter: q bf16*SCQ; k bf16 + k fp32; v fp32 + v^T bf16
template<int MODE>
__global__ __launch_bounds__(512)
void gemm256(const bf16_t* __restrict__ A, const bf16_t* __restrict__ Bm,
             const int K, const int N, const int nbx,
             float* __restrict__ Cf, bf16_t* __restrict__ qbf,
             bf16_t* __restrict__ kbt, float* __restrict__ kf,
             float* __restrict__ vf, bf16_t* __restrict__ vtb) {
  __shared__ bf16_t As[4][256 * 32];
  __shared__ bf16_t Bs[4][256 * 32];
  const int t = threadIdx.x, w = t >> 6, lane = t & 63;
  const int fr = lane & 15, fq = lane >> 4;
  // XCD-chunked bijective swizzle (grid % 8 == 0), N-major flatten
  const int cpx = gridDim.x >> 3;
  const int orig = blockIdx.x;
  const int wg = (orig & 7) * cpx + (orig >> 3);
  const int bm = wg % nbx, bn = wg / nbx;
  const int row0 = bm * 256, col0 = bn * 256;
  const int wm = (w >> 2) * 128, wn = (w & 3) * 64;

  // staging: 2 x 16B per matrix per thread per K-tile; linear idx j*512+t
  const int i0 = t, i1 = 512 + t;
  const int r0 = i0 >> 2, c0 = i0 & 3;
  const int r1 = i1 >> 2, c1 = i1 & 3;
  const bf16_t* A0 = A + (size_t)(row0 + r0) * K + ((c0 ^ ((r0 >> 1) & 3)) * 8);
  const bf16_t* A1 = A + (size_t)(row0 + r1) * K + ((c1 ^ ((r1 >> 1) & 3)) * 8);
  const bf16_t* B0 = Bm + (size_t)(col0 + r0) * K + ((c0 ^ ((r0 >> 1) & 3)) * 8);
  const bf16_t* B1 = Bm + (size_t)(col0 + r1) * K + ((c1 ^ ((r1 >> 1) & 3)) * 8);

  const int NT = K >> 5;
  f32x4 acc[8][4] = {};

#define STAGE(TT)                                                      \
  {                                                                    \
    const int sl_ = (TT) & 3;                                          \
    const size_t ko_ = (size_t)(TT) * 32;                              \
    gl16(A0 + ko_, (char*)(&As[sl_][0]) + w * 1024);                   \
    gl16(A1 + ko_, (char*)(&As[sl_][0]) + 8192 + w * 1024);            \
    gl16(B0 + ko_, (char*)(&Bs[sl_][0]) + w * 1024);                   \
    gl16(B1 + ko_, (char*)(&Bs[sl_][0]) + 8192 + w * 1024);            \
  }

  STAGE(0); STAGE(1); STAGE(2);

  for (int T = 0; T < NT; ++T) {
    // issue stage T+3, then wait for tile T's 4 loads (12 newer stay in flight)
    if (T + 3 < NT) {
      STAGE(T + 3);
      asm volatile("s_waitcnt vmcnt(12)" ::: "memory");
    } else if (T + 3 == NT) {
      asm volatile("s_waitcnt vmcnt(8)" ::: "memory");
    } else if (T + 2 == NT) {
      asm volatile("s_waitcnt vmcnt(4)" ::: "memory");
    } else {
      asm volatile("s_waitcnt vmcnt(0)" ::: "memory");
    }
    asm volatile("s_barrier" ::: "memory");   // everyone's tile T staged

    const bf16_t* al = &As[T & 3][0];
    const bf16_t* bl = &Bs[T & 3][0];
    bf16x8 bfv[4];
#pragma unroll
    for (int n = 0; n < 4; ++n) {
      int rb = wn + n * 16 + fr;
      bfv[n] = *(const bf16x8*)(bl + rb * 32 + ((fq ^ ((rb >> 1) & 3)) * 8));
    }
    __builtin_amdgcn_s_setprio(1);
#pragma unroll
    for (int f = 0; f < 8; ++f) {
      int ra = wm + f * 16 + fr;
      bf16x8 af = *(const bf16x8*)(al + ra * 32 + ((fq ^ ((ra >> 1) & 3)) * 8));
#pragma unroll
      for (int n = 0; n < 4; ++n)
        acc[f][n] = __builtin_amdgcn_mfma_f32_16x16x32_bf16(af, bfv[n], acc[f][n], 0, 0, 0);
    }
    __builtin_amdgcn_s_setprio(0);
    asm volatile("s_barrier" ::: "memory");   // all reads of slot T&3 done
  }
#undef STAGE

  // epilogue: C/D layout col=lane&15, row=(lane>>4)*4+reg
#pragma unroll
  for (int f = 0; f < 8; ++f) {
#pragma unroll
    for (int jn = 0; jn < 4; ++jn) {
#pragma unroll
      for (int r = 0; r < 4; ++r) {
        int m = row0 + wm + f * 16 + fq * 4 + r;
        int n = col0 + wn + jn * 16 + fr;
        float v = acc[f][jn][r];
        if (MODE == 0) {
          Cf[(size_t)m * N + n] = v;
        } else {
          int b = m >> 11, s = m & 2047;
          if (n < DM) {
            int h = n >> 7, d = n & 127;
            qbf[(((size_t)(b * NH + h)) * SS + s) * HD + d] = (bf16_t)(v * SCQ);
          } else if (n < 2 * DM) {
            int nn = n - DM, h = nn >> 7, d = nn & 127;
            size_t o = (((size_t)(b * NH + h)) * SS + s) * HD + d;
            kbt[o] = (bf16_t)v;
            kf[o] = v;
          } else {
            int nn = n - 2 * DM, h = nn >> 7, d = nn & 127;
            size_t o = (((size_t)(b * NH + h)) * SS + s) * HD + d;
            vf[o] = v;
            vtb[((size_t)(b * NH + h)) * (HD * SS) + (size_t)d * SS + s] = (bf16_t)v;
          }
        }
      }
    }
  }
}

// ---------------- causal flash attention v4 --------------------------------
// 1024 blocks (XCD-chunked), 256 thr = 4 waves. QB=128 (32 q/wave, 32x32 mfma),
// KVB=64. Swapped QK^T (P lane-local); P->A-frag rebuilt in-register via
// cvt_pk + shfl_xor(32) half-exchange. K/V^T staged bf16 via global_load_lds
// (per-lane inverse-swizzled source), double-buffered; barrier -> issue next
// tile gl16 -> compute cur.
__global__ __launch_bounds__(256, 2)
void attn_fwd4(const bf16_t* __restrict__ qbf, const bf16_t* __restrict__ kbf,
               const bf16_t* __restrict__ vt, bf16_t* __restrict__ aout) {
  __shared__ bf16_t Ks[2][64 * 128];   // [row s][256B = 16 chunks], chunk ^= (row&15)
  __shared__ bf16_t Vs[2][64 * 128];   // row R: d = 2R + (c>>3), k8 = c&7; chunk ^= (R&15)
  const int t = threadIdx.x, w = t >> 6, lane = t & 63;
  const int l31 = lane & 31, hi = lane >> 5;
  const int orig = blockIdx.x;
  const int wg = (orig & 7) * 128 + (orig >> 3);   // XCD-chunked, bijective (1024%8==0)
  const int bh = wg >> 4;
  const int qt = 15 - (wg & 15);                   // big-first within each XCD chunk
  const int q0 = qt * 128;
  const int nt = 2 * qt + 2;
  const size_t bh_off = (size_t)bh * SS * HD;
  const char* kbase = (const char*)(kbf + bh_off);
  const char* vbase = (const char*)(vt + bh_off);

  // per-lane staging sources (inverse-swizzled so linear LDS dest => swizzled tile)
  const char* ksrc[4];
  const char* vsrc[4];
#pragma unroll
  for (int i = 0; i < 4; ++i) {
    int r = (w * 4 + i) * 4 + (lane >> 4);
    int c = (lane & 15) ^ (r & 15);
    ksrc[i] = kbase + r * 256 + c * 16;
    int d = 2 * r + (c >> 3);
    vsrc[i] = vbase + (size_t)d * (SS * 2) + (c & 7) * 16;
  }

  // Q fragments (B-operand): col q = q0+w*32+l31, k(d) = ds*16 + hi*8 + e
  bf16x8 qfr[8];
  {
    const char* qrow = (const char*)(qbf + bh_off + (size_t)(q0 + w * 32 + l31) * HD);
#pragma unroll
    for (int ds = 0; ds < 8; ++ds)
      qfr[ds] = *(const bf16x8*)(qrow + ds * 32 + hi * 16);
  }

  // prologue: stage tile 0 into buf 0
#pragma unroll
  for (int i = 0; i < 4; ++i) {
    gl16(ksrc[i], (char*)(&Ks[0][0]) + (w * 4 + i) * 1024);
    gl16(vsrc[i], (char*)(&Vs[0][0]) + (w * 4 + i) * 1024);
    ksrc[i] += 16384;   // +64 kv rows * 256B
    vsrc[i] += 128;     // +64 kv cols * 2B
  }

  float mrow = -3.0e38f, lrow = 0.f;
  f32x16 accO[4] = {};   // O[q=(r&3)+8*(r>>2)+4hi][d=dt*32+l31]

  // In-reg P->A-frag. Lane owns P^T[crow(r,hi)][q=l31]; A-frag needs
  // P[q=l31][k=slot*16+hi*8+e]. Per 4-word group {A,B,C,D}=W[4g..4g+3]:
  //   word0 = hi ? xC : A ; word1 = hi ? xD : B
  //   word2 = hi ? C : xA ; word3 = hi ? D : xB     (x = shfl_xor 32)
  auto make_pa = [&](const f32x16& sv, bf16x8& paA, bf16x8& paB) {
    unsigned W[8];
#pragma unroll
    for (int m = 0; m < 8; ++m) {
      float lo = sv[2 * m], hh = sv[2 * m + 1];
      asm("v_cvt_pk_bf16_f32 %0, %1, %2" : "=v"(W[m]) : "v"(lo), "v"(hh));
    }
#pragma unroll
    for (int g = 0; g < 2; ++g) {
      unsigned A = W[4 * g], B = W[4 * g + 1], C = W[4 * g + 2], D = W[4 * g + 3];
      unsigned xA = (unsigned)__shfl_xor((int)A, 32, 64);
      unsigned xB = (unsigned)__shfl_xor((int)B, 32, 64);
      unsigned xC = (unsigned)__shfl_xor((int)C, 32, 64);
      unsigned xD = (unsigned)__shfl_xor((int)D, 32, 64);
      uint4v u;
      u.x = hi ? xC : A;
      u.y = hi ? xD : B;
      u.z = hi ? C : xA;
      u.w = hi ? D : xB;
      if (g == 0) paA = __builtin_bit_cast(bf16x8, u);
      else        paB = __builtin_bit_cast(bf16x8, u);
    }
  };

  for (int kt = 0; kt < nt; ++kt) {
    const int cur = kt & 1;
    __syncthreads();   // vmcnt(0) drain: tile kt staged; prev readers of buf[cur^1] done

    // ---- issue next tile's gl16 into buf[cur^1]; latency hides under compute
    if (kt + 1 < nt) {
#pragma unroll
      for (int i = 0; i < 4; ++i) {
        gl16(ksrc[i], (char*)(&Ks[cur ^ 1][0]) + (w * 4 + i) * 1024);
        gl16(vsrc[i], (char*)(&Vs[cur ^ 1][0]) + (w * 4 + i) * 1024);
        ksrc[i] += 16384;
        vsrc[i] += 128;
      }
    }

    // ---- swapped QK^T: S^T[k][q] per 32-k block (kb=0: s0, kb=1: s1)
    const char* kl = (const char*)&Ks[cur][0];
    f32x16 s0 = {}, s1 = {};
    const int rck = l31 & 15;   // (row & 15) same for rows l31 and 32+l31
    __builtin_amdgcn_s_setprio(1);
#pragma unroll
    for (int ds = 0; ds < 8; ++ds) {
      int ch = ((2 * ds + hi) ^ rck) << 4;
      bf16x8 kf0 = *(const bf16x8*)(kl + l31 * 256 + ch);
      s0 = __builtin_amdgcn_mfma_f32_32x32x16_bf16(kf0, qfr[ds], s0, 0, 0, 0);
      bf16x8 kf1 = *(const bf16x8*)(kl + (32 + l31) * 256 + ch);
      s1 = __builtin_amdgcn_mfma_f32_32x32x16_bf16(kf1, qfr[ds], s1, 0, 0, 0);
    }
    __builtin_amdgcn_s_setprio(0);

    // ---- mask (diag tiles) + online softmax in exp2 domain
    const int kv0 = kt * 64;
    if (kt >= 2 * qt) {
      const int qg = q0 + w * 32 + l31;
#pragma unroll
      for (int r = 0; r < 16; ++r) {
        int klo = kv0 + (r & 3) + 8 * (r >> 2) + 4 * hi;
        if (klo > qg) s0[r] = -3.0e38f;
        if (klo + 32 > qg) s1[r] = -3.0e38f;
      }
    }
    float rm = s0[0];
#pragma unroll
    for (int r = 1; r < 16; ++r) rm = fmaxf(rm, s0[r]);
#pragma unroll
    for (int r = 0; r < 16; ++r) rm = fmaxf(rm, s1[r]);
    rm = fmaxf(rm, __shfl_xor(rm, 32, 64));
    if (__ballot(rm > mrow + 8.0f)) {       // defer-max: rescale only on real growth
      float mnew = fmaxf(mrow, rm);
      float fct = __builtin_amdgcn_exp2f(mrow - mnew);
      mrow = mnew;
      lrow *= fct;
#pragma unroll
      for (int r = 0; r < 16; ++r) {
        float f = __shfl(fct, (r & 3) + 8 * (r >> 2) + 4 * hi, 64);
        accO[0][r] *= f; accO[1][r] *= f; accO[2][r] *= f; accO[3][r] *= f;
      }
    }
    float ss = 0.f;
#pragma unroll
    for (int r = 0; r < 16; ++r) { float p = __builtin_amdgcn_exp2f(s0[r] - mrow); s0[r] = p; ss += p; }
#pragma unroll
    for (int r = 0; r < 16; ++r) { float p = __builtin_amdgcn_exp2f(s1[r] - mrow); s1[r] = p; ss += p; }
    ss += __shfl_xor(ss, 32, 64);
    lrow += ss;

    // ---- P -> PV A-fragments (in-register, no LDS round trip)
    bf16x8 pa00, pa01, pa10, pa11;
    make_pa(s0, pa00, pa01);   // k slots 0,1 (k=0..31)
    make_pa(s1, pa10, pa11);   // k slots 2,3 (k=32..63)

    // ---- PV: O[32q x 128d] += P[32q x 64k] * V[64k x 128d]
    const char* vl = (const char*)&Vs[cur][0];
    __builtin_amdgcn_s_setprio(1);
#pragma unroll
    for (int dt = 0; dt < 4; ++dt) {
      int R = dt * 16 + (l31 >> 1);
      int cb = (l31 & 1) << 3;      // d-half*8
      int rx = R & 15;
      bf16x8 v00 = *(const bf16x8*)(vl + R * 256 + (((cb + 0 + hi) ^ rx) << 4));
      accO[dt] = __builtin_amdgcn_mfma_f32_32x32x16_bf16(pa00, v00, accO[dt], 0, 0, 0);
      bf16x8 v01 = *(const bf16x8*)(vl + R * 256 + (((cb + 2 + hi) ^ rx) << 4));
      accO[dt] = __builtin_amdgcn_mfma_f32_32x32x16_bf16(pa01, v01, accO[dt], 0, 0, 0);
      bf16x8 v10 = *(const bf16x8*)(vl + R * 256 + (((cb + 4 + hi) ^ rx) << 4));
      accO[dt] = __builtin_amdgcn_mfma_f32_32x32x16_bf16(pa10, v10, accO[dt], 0, 0, 0);
      bf16x8 v11 = *(const bf16x8*)(vl + R * 256 + (((cb + 6 + hi) ^ rx) << 4));
      accO[dt] = __builtin_amdgcn_mfma_f32_32x32x16_bf16(pa11, v11, accO[dt], 0, 0, 0);
    }
    __builtin_amdgcn_s_setprio(0);
  }

  // ---- normalize + write attn out as [b, s, h*128+d] bf16
  const int b = bh >> 4, h = bh & 15;
#pragma unroll
  for (int r = 0; r < 16; ++r) {
    int qr = (r & 3) + 8 * (r >> 2) + 4 * hi;
    float inv = __builtin_amdgcn_rcpf(__shfl(lrow, qr, 64));
    int srow = q0 + w * 32 + qr;
    bf16_t* orow = aout + ((size_t)(b * SS + srow)) * DM + h * HD + l31;
    orow[0]  = (bf16_t)(accO[0][r] * inv);
    orow[32] = (bf16_t)(accO[1][r] * inv);
    orow[64] = (bf16_t)(accO[2][r] * inv);
    orow[96] = (bf16_t)(accO[3][r] * inv);
  }
}

// ---------------- launch ---------------------------------------------------
extern "C" void kernel_launch(void* const* d_in, const int* in_sizes, int n_in,
                              void* d_out, int out_size, void* d_ws, size_t ws_size,
                              hipStream_t stream) {
  (void)in_sizes; (void)n_in; (void)out_size; (void)ws_size;
  const float* x  = (const float*)d_in[0];
  const float* Wq = (const float*)d_in[1];
  const float* Wk = (const float*)d_in[2];
  const float* Wv = (const float*)d_in[3];
  const float* Wo = (const float*)d_in[4];

  float* y  = (float*)d_out;                       // [8192, 2048] fp32
  float* kf = y + (size_t)BS * DM;                 // fp32 [b,h,s,d] (output)
  float* vf = kf + (size_t)BS * DM;                // fp32 [b,h,s,d] (output)

  // ws (max 96MB live):
  //  [0,32M)  xbf (conv->gemm1), then abf (attn out -> out-proj)
  //  [32,64M) qbf (gemm1->attn), then wobf (after attn -> out-proj)
  //  [64,88M) wqkv (conv->gemm1)
  // d_out y region doubles as: kbt bf16 [0,32M of y), vtb bf16 V^T [32,64M of y)
  // (both dead once attn completes; y written last by gemm0)
  char* ws = (char*)d_ws;
  bf16_t* xbf  = (bf16_t*)ws;
  bf16_t* abf  = xbf;
  bf16_t* qbf  = (bf16_t*)(ws + (size_t)32 * 1024 * 1024);
  bf16_t* wobf = qbf;
  bf16_t* wqkv = (bf16_t*)(ws + (size_t)64 * 1024 * 1024);
  bf16_t* kbt  = (bf16_t*)y;
  bf16_t* vtb  = (bf16_t*)((char*)y + (size_t)32 * 1024 * 1024);

  conv_f32_bf16<<<2048, 256, 0, stream>>>(x, (unsigned short*)xbf, BS * DM / 4);
  conv_f32_bf16<<<512, 256, 0, stream>>>(Wq, (unsigned short*)wqkv, DM * DM / 4);
  conv_f32_bf16<<<512, 256, 0, stream>>>(Wk, (unsigned short*)(wqkv + (size_t)DM * DM), DM * DM / 4);
  conv_f32_bf16<<<512, 256, 0, stream>>>(Wv, (unsigned short*)(wqkv + 2 * (size_t)DM * DM), DM * DM / 4);

  // QKV projection: M=8192 (32 M-blocks), N=6144 (24 N-blocks) -> 768 wgs
  gemm256<1><<<768, 512, 0, stream>>>(
      xbf, wqkv, DM, NQKV, 32, nullptr, qbf, kbt, kf, vf, vtb);

  attn_fwd4<<<1024, 256, 0, stream>>>(qbf, kbt, vtb, abf);

  conv_f32_bf16<<<512, 256, 0, stream>>>(Wo, (unsigned short*)wobf, DM * DM / 4);

  // out-proj: M=8192 (32), N=2048 (8) -> 256 wgs
  gemm256<0><<<256, 512, 0, stream>>>(
      abf, wobf, DM, DM, 32, y, nullptr, nullptr, nullptr, nullptr, nullptr);
}

// Round 6
// 510.335 us; speedup vs baseline: 3.0180x; 1.0372x over previous
//
#include <hip/hip_runtime.h>
#include <stdint.h>

#define DM 2048
#define NH 16
#define HD 128
#define BB 4
#define SS 2048
#define BS (BB*SS)      // 8192 rows
#define NQKV (3*DM)     // 6144
// softmax scale folded into Q at GEMM epilogue, in exp2 domain:
// 1/sqrt(128) * log2(e)
#define SCQ 0.12751744565f

typedef __bf16 bf16_t;
typedef __attribute__((ext_vector_type(8))) __bf16 bf16x8;
typedef __attribute__((ext_vector_type(4))) float f32x4;
typedef __attribute__((ext_vector_type(16))) float f32x16;
typedef __attribute__((ext_vector_type(4))) float float4v;
typedef __attribute__((ext_vector_type(4))) unsigned int uint4v;
typedef __attribute__((ext_vector_type(4))) unsigned short ushort4v;
typedef __attribute__((ext_vector_type(8))) unsigned short ushort8;

__device__ __forceinline__ unsigned short f2bf(float f) {
  unsigned u = __float_as_uint(f);
  u += 0x7fffu + ((u >> 16) & 1u);
  return (unsigned short)(u >> 16);
}

// async global->LDS, 16B per lane; dest = (wave-uniform) l + lane*16
__device__ __forceinline__ void gl16(const void* g, void* l) {
  __builtin_amdgcn_global_load_lds(
      (const __attribute__((address_space(1))) unsigned int*)(unsigned long long)g,
      (__attribute__((address_space(3))) unsigned int*)(unsigned int)(unsigned long long)l,
      16, 0, 0);
}

// ---------------- fp32 -> bf16 conversion (vectorized, grid-stride) -------
__global__ void conv_f32_bf16(const float* __restrict__ in,
                              unsigned short* __restrict__ out, int n4) {
  int i = blockIdx.x * blockDim.x + threadIdx.x;
  int stride = gridDim.x * blockDim.x;
  for (; i < n4; i += stride) {
    float4v v = ((const float4v*)in)[i];
    ushort4v o;
    o.x = f2bf(v.x); o.y = f2bf(v.y); o.z = f2bf(v.z); o.w = f2bf(v.w);
    ((ushort4v*)out)[i] = o;
  }
}

// ---------------- GEMM C = A * B^T, 256x256 tile, BK=64, 4-phase/tile -----
// 512 thr = 8 waves (2M x 4N), per-wave 128x64, mfma 16x16x32 bf16.
// LDS: 2 x (A[256][64] + B[256][64]) bf16 = 128KB, chunk-XOR c^=(r&7).
// Schedule per K-tile (8-phase-style, counted vmcnt, never 0 mid-loop):
//   [stage next-A (4 gl16); vmcnt(4); s_barrier]          <- tile T ready
//   P0: ds B(8)+A01(4); barrier; 16 MFMA; barrier
//   P1: ds A23(4); stage next-B (4 gl16); barrier; 16 MFMA; barrier
//   P2: ds A45(4); barrier; 16 MFMA; barrier
//   P3: ds A67(4); barrier; 16 MFMA; barrier
// MODE 0: C -> fp32 row-major [M,N]
// MODE 1: QKV scatter: q bf16*SCQ; k bf16 + k fp32; v fp32 + v^T bf16
template<int MODE>
__global__ __launch_bounds__(512)
void gemm8p(const bf16_t* __restrict__ A, const bf16_t* __restrict__ Bm,
            const int K, const int N, const int nbx,
            float* __restrict__ Cf, bf16_t* __restrict__ qbf,
            bf16_t* __restrict__ kbt, float* __restrict__ kf,
            float* __restrict__ vf, bf16_t* __restrict__ vtb) {
  __shared__ bf16_t As[2][256 * 64];
  __shared__ bf16_t Bs[2][256 * 64];
  const int t = threadIdx.x, w = t >> 6, lane = t & 63;
  const int fr = lane & 15, fq = lane >> 4;
  // XCD-chunked bijective swizzle (grid % 8 == 0), N-major flatten
  const int cpx = gridDim.x >> 3;
  const int orig = blockIdx.x;
  const int wg = (orig & 7) * cpx + (orig >> 3);
  const int bm = wg % nbx, bn = wg / nbx;
  const int row0 = bm * 256, col0 = bn * 256;
  const int wm = (w >> 2) * 128, wn = (w & 3) * 64;

  // staging: 4 x 16B per matrix per thread per K-tile; unit u = j*512 + t
  const bf16_t* Asrc[4];
  const bf16_t* Bsrc[4];
  int dst[4];
#pragma unroll
  for (int j = 0; j < 4; ++j) {
    int u = j * 512 + t, r = u >> 3, c = u & 7;
    Asrc[j] = A + (size_t)(row0 + r) * K + ((c ^ (r & 7)) * 8);
    Bsrc[j] = Bm + (size_t)(col0 + r) * K + ((c ^ (r & 7)) * 8);
    dst[j] = u * 16;
  }
  const int NT = K >> 6;
  f32x4 acc[8][4] = {};

  // prologue: tile 0 A then B (8 loads in flight)
#pragma unroll
  for (int j = 0; j < 4; ++j) gl16(Asrc[j], (char*)(&As[0][0]) + dst[j]);
#pragma unroll
  for (int j = 0; j < 4; ++j) gl16(Bsrc[j], (char*)(&Bs[0][0]) + dst[j]);

  for (int T = 0; T < NT; ++T) {
    const bf16_t* al = &As[T & 1][0];
    const bf16_t* bl = &Bs[T & 1][0];
    char* Ad = (char*)(&As[(T & 1) ^ 1][0]);
    char* Bd = (char*)(&Bs[(T & 1) ^ 1][0]);
    const size_t ko = (size_t)(T + 1) * 64;

    // ---- readiness: issue next-tile A, wait own tile-T loads, barrier
    if (T + 1 < NT) {
#pragma unroll
      for (int j = 0; j < 4; ++j) gl16(Asrc[j] + ko, Ad + dst[j]);
      asm volatile("s_waitcnt vmcnt(4)" ::: "memory");
    } else {
      asm volatile("s_waitcnt vmcnt(0)" ::: "memory");
    }
    asm volatile("s_barrier" ::: "memory");

    auto LDA = [&](int f, int ks) {
      int ra = wm + f * 16 + fr;
      return *(const bf16x8*)(al + ra * 64 + (((fq + ks * 4) ^ (ra & 7)) * 8));
    };

    // ---- phase 0: read all B + A f0,f1; MFMA quad 0
    bf16x8 bfv[4][2];
#pragma unroll
    for (int n = 0; n < 4; ++n) {
      int rb = wn + n * 16 + fr;
#pragma unroll
      for (int ks = 0; ks < 2; ++ks)
        bfv[n][ks] = *(const bf16x8*)(bl + rb * 64 + (((fq + ks * 4) ^ (rb & 7)) * 8));
    }
    {
      bf16x8 a00 = LDA(0, 0), a01 = LDA(0, 1), a10 = LDA(1, 0), a11 = LDA(1, 1);
      __builtin_amdgcn_s_barrier();
      __builtin_amdgcn_s_setprio(1);
#pragma unroll
      for (int n = 0; n < 4; ++n) {
        acc[0][n] = __builtin_amdgcn_mfma_f32_16x16x32_bf16(a00, bfv[n][0], acc[0][n], 0, 0, 0);
        acc[1][n] = __builtin_amdgcn_mfma_f32_16x16x32_bf16(a10, bfv[n][0], acc[1][n], 0, 0, 0);
      }
#pragma unroll
      for (int n = 0; n < 4; ++n) {
        acc[0][n] = __builtin_amdgcn_mfma_f32_16x16x32_bf16(a01, bfv[n][1], acc[0][n], 0, 0, 0);
        acc[1][n] = __builtin_amdgcn_mfma_f32_16x16x32_bf16(a11, bfv[n][1], acc[1][n], 0, 0, 0);
      }
      __builtin_amdgcn_s_setprio(0);
      __builtin_amdgcn_s_barrier();
    }
    // ---- phase 1: read A f2,f3 + stage next-tile B; MFMA quad 1
    {
      bf16x8 a00 = LDA(2, 0), a01 = LDA(2, 1), a10 = LDA(3, 0), a11 = LDA(3, 1);
      if (T + 1 < NT) {
#pragma unroll
        for (int j = 0; j < 4; ++j) gl16(Bsrc[j] + ko, Bd + dst[j]);
      }
      __builtin_amdgcn_s_barrier();
      __builtin_amdgcn_s_setprio(1);
#pragma unroll
      for (int n = 0; n < 4; ++n) {
        acc[2][n] = __builtin_amdgcn_mfma_f32_16x16x32_bf16(a00, bfv[n][0], acc[2][n], 0, 0, 0);
        acc[3][n] = __builtin_amdgcn_mfma_f32_16x16x32_bf16(a10, bfv[n][0], acc[3][n], 0, 0, 0);
      }
#pragma unroll
      for (int n = 0; n < 4; ++n) {
        acc[2][n] = __builtin_amdgcn_mfma_f32_16x16x32_bf16(a01, bfv[n][1], acc[2][n], 0, 0, 0);
        acc[3][n] = __builtin_amdgcn_mfma_f32_16x16x32_bf16(a11, bfv[n][1], acc[3][n], 0, 0, 0);
      }
      __builtin_amdgcn_s_setprio(0);
      __builtin_amdgcn_s_barrier();
    }
    // ---- phase 2: read A f4,f5; MFMA quad 2
    {
      bf16x8 a00 = LDA(4, 0), a01 = LDA(4, 1), a10 = LDA(5, 0), a11 = LDA(5, 1);
      __builtin_amdgcn_s_barrier();
      __builtin_amdgcn_s_setprio(1);
#pragma unroll
      for (int n = 0; n < 4; ++n) {
        acc[4][n] = __builtin_amdgcn_mfma_f32_16x16x32_bf16(a00, bfv[n][0], acc[4][n], 0, 0, 0);
        acc[5][n] = __builtin_amdgcn_mfma_f32_16x16x32_bf16(a10, bfv[n][0], acc[5][n], 0, 0, 0);
      }
#pragma unroll
      for (int n = 0; n < 4; ++n) {
        acc[4][n] = __builtin_amdgcn_mfma_f32_16x16x32_bf16(a01, bfv[n][1], acc[4][n], 0, 0, 0);
        acc[5][n] = __builtin_amdgcn_mfma_f32_16x16x32_bf16(a11, bfv[n][1], acc[5][n], 0, 0, 0);
      }
      __builtin_amdgcn_s_setprio(0);
      __builtin_amdgcn_s_barrier();
    }
    // ---- phase 3: read A f6,f7; MFMA quad 3
    {
      bf16x8 a00 = LDA(6, 0), a01 = LDA(6, 1), a10 = LDA(7, 0), a11 = LDA(7, 1);
      __builtin_amdgcn_s_barrier();
      __builtin_amdgcn_s_setprio(1);
#pragma unroll
      for (int n = 0; n < 4; ++n) {
        acc[6][n] = __builtin_amdgcn_mfma_f32_16x16x32_bf16(a00, bfv[n][0], acc[6][n], 0, 0, 0);
        acc[7][n] = __builtin_amdgcn_mfma_f32_16x16x32_bf16(a10, bfv[n][0], acc[7][n], 0, 0, 0);
      }
#pragma unroll
      for (int n = 0; n < 4; ++n) {
        acc[6][n] = __builtin_amdgcn_mfma_f32_16x16x32_bf16(a01, bfv[n][1], acc[6][n], 0, 0, 0);
        acc[7][n] = __builtin_amdgcn_mfma_f32_16x16x32_bf16(a11, bfv[n][1], acc[7][n], 0, 0, 0);
      }
      __builtin_amdgcn_s_setprio(0);
      __builtin_amdgcn_s_barrier();
    }
  }

  // epilogue: C/D layout col=lane&15, row=(lane>>4)*4+reg
#pragma unroll
  for (int f = 0; f < 8; ++f) {
#pragma unroll
    for (int jn = 0; jn < 4; ++jn) {
#pragma unroll
      for (int r = 0; r < 4; ++r) {
        int m = row0 + wm + f * 16 + fq * 4 + r;
        int n = col0 + wn + jn * 16 + fr;
        float v = acc[f][jn][r];
        if (MODE == 0) {
          Cf[(size_t)m * N + n] = v;
        } else {
          int b = m >> 11, s = m & 2047;
          if (n < DM) {
            int h = n >> 7, d = n & 127;
            qbf[(((size_t)(b * NH + h)) * SS + s) * HD + d] = (bf16_t)(v * SCQ);
          } else if (n < 2 * DM) {
            int nn = n - DM, h = nn >> 7, d = nn & 127;
            size_t o = (((size_t)(b * NH + h)) * SS + s) * HD + d;
            kbt[o] = (bf16_t)v;
            kf[o] = v;
          } else {
            int nn = n - 2 * DM, h = nn >> 7, d = nn & 127;
            size_t o = (((size_t)(b * NH + h)) * SS + s) * HD + d;
            vf[o] = v;
            vtb[((size_t)(b * NH + h)) * (HD * SS) + (size_t)d * SS + s] = (bf16_t)v;
          }
        }
      }
    }
  }
}

// ---------------- causal flash attention v4 --------------------------------
// 1024 blocks (XCD-chunked), 256 thr = 4 waves. QB=128 (32 q/wave, 32x32 mfma),
// KVB=64. Swapped QK^T (P lane-local); P->A-frag rebuilt in-register via
// cvt_pk + shfl_xor(32) half-exchange. K/V^T staged bf16 via global_load_lds
// (per-lane inverse-swizzled source), double-buffered; barrier -> issue next
// tile gl16 -> compute cur.
__global__ __launch_bounds__(256, 2)
void attn_fwd4(const bf16_t* __restrict__ qbf, const bf16_t* __restrict__ kbf,
               const bf16_t* __restrict__ vt, bf16_t* __restrict__ aout) {
  __shared__ bf16_t Ks[2][64 * 128];   // [row s][256B = 16 chunks], chunk ^= (row&15)
  __shared__ bf16_t Vs[2][64 * 128];   // row R: d = 2R + (c>>3), k8 = c&7; chunk ^= (R&15)
  const int t = threadIdx.x, w = t >> 6, lane = t & 63;
  const int l31 = lane & 31, hi = lane >> 5;
  const int orig = blockIdx.x;
  const int wg = (orig & 7) * 128 + (orig >> 3);   // XCD-chunked, bijective (1024%8==0)
  const int bh = wg >> 4;
  const int qt = 15 - (wg & 15);                   // big-first within each XCD chunk
  const int q0 = qt * 128;
  const int nt = 2 * qt + 2;
  const size_t bh_off = (size_t)bh * SS * HD;
  const char* kbase = (const char*)(kbf + bh_off);
  const char* vbase = (const char*)(vt + bh_off);

  // per-lane staging sources (inverse-swizzled so linear LDS dest => swizzled tile)
  const char* ksrc[4];
  const char* vsrc[4];
#pragma unroll
  for (int i = 0; i < 4; ++i) {
    int r = (w * 4 + i) * 4 + (lane >> 4);
    int c = (lane & 15) ^ (r & 15);
    ksrc[i] = kbase + r * 256 + c * 16;
    int d = 2 * r + (c >> 3);
    vsrc[i] = vbase + (size_t)d * (SS * 2) + (c & 7) * 16;
  }

  // Q fragments (B-operand): col q = q0+w*32+l31, k(d) = ds*16 + hi*8 + e
  bf16x8 qfr[8];
  {
    const char* qrow = (const char*)(qbf + bh_off + (size_t)(q0 + w * 32 + l31) * HD);
#pragma unroll
    for (int ds = 0; ds < 8; ++ds)
      qfr[ds] = *(const bf16x8*)(qrow + ds * 32 + hi * 16);
  }

  // prologue: stage tile 0 into buf 0
#pragma unroll
  for (int i = 0; i < 4; ++i) {
    gl16(ksrc[i], (char*)(&Ks[0][0]) + (w * 4 + i) * 1024);
    gl16(vsrc[i], (char*)(&Vs[0][0]) + (w * 4 + i) * 1024);
    ksrc[i] += 16384;   // +64 kv rows * 256B
    vsrc[i] += 128;     // +64 kv cols * 2B
  }

  float mrow = -3.0e38f, lrow = 0.f;
  f32x16 accO[4] = {};   // O[q=(r&3)+8*(r>>2)+4hi][d=dt*32+l31]

  // In-reg P->A-frag. Lane owns P^T[crow(r,hi)][q=l31]; A-frag needs
  // P[q=l31][k=slot*16+hi*8+e]. Per 4-word group {A,B,C,D}=W[4g..4g+3]:
  //   word0 = hi ? xC : A ; word1 = hi ? xD : B
  //   word2 = hi ? C : xA ; word3 = hi ? D : xB     (x = shfl_xor 32)
  auto make_pa = [&](const f32x16& sv, bf16x8& paA, bf16x8& paB) {
    unsigned W[8];
#pragma unroll
    for (int m = 0; m < 8; ++m) {
      float lo = sv[2 * m], hh = sv[2 * m + 1];
      asm("v_cvt_pk_bf16_f32 %0, %1, %2" : "=v"(W[m]) : "v"(lo), "v"(hh));
    }
#pragma unroll
    for (int g = 0; g < 2; ++g) {
      unsigned A = W[4 * g], B = W[4 * g + 1], C = W[4 * g + 2], D = W[4 * g + 3];
      unsigned xA = (unsigned)__shfl_xor((int)A, 32, 64);
      unsigned xB = (unsigned)__shfl_xor((int)B, 32, 64);
      unsigned xC = (unsigned)__shfl_xor((int)C, 32, 64);
      unsigned xD = (unsigned)__shfl_xor((int)D, 32, 64);
      uint4v u;
      u.x = hi ? xC : A;
      u.y = hi ? xD : B;
      u.z = hi ? C : xA;
      u.w = hi ? D : xB;
      if (g == 0) paA = __builtin_bit_cast(bf16x8, u);
      else        paB = __builtin_bit_cast(bf16x8, u);
    }
  };

  for (int kt = 0; kt < nt; ++kt) {
    const int cur = kt & 1;
    __syncthreads();   // vmcnt(0) drain: tile kt staged; prev readers of buf[cur^1] done

    // ---- issue next tile's gl16 into buf[cur^1]; latency hides under compute
    if (kt + 1 < nt) {
#pragma unroll
      for (int i = 0; i < 4; ++i) {
        gl16(ksrc[i], (char*)(&Ks[cur ^ 1][0]) + (w * 4 + i) * 1024);
        gl16(vsrc[i], (char*)(&Vs[cur ^ 1][0]) + (w * 4 + i) * 1024);
        ksrc[i] += 16384;
        vsrc[i] += 128;
      }
    }

    // ---- swapped QK^T: S^T[k][q] per 32-k block (kb=0: s0, kb=1: s1)
    const char* kl = (const char*)&Ks[cur][0];
    f32x16 s0 = {}, s1 = {};
    const int rck = l31 & 15;   // (row & 15) same for rows l31 and 32+l31
    __builtin_amdgcn_s_setprio(1);
#pragma unroll
    for (int ds = 0; ds < 8; ++ds) {
      int ch = ((2 * ds + hi) ^ rck) << 4;
      bf16x8 kf0 = *(const bf16x8*)(kl + l31 * 256 + ch);
      s0 = __builtin_amdgcn_mfma_f32_32x32x16_bf16(kf0, qfr[ds], s0, 0, 0, 0);
      bf16x8 kf1 = *(const bf16x8*)(kl + (32 + l31) * 256 + ch);
      s1 = __builtin_amdgcn_mfma_f32_32x32x16_bf16(kf1, qfr[ds], s1, 0, 0, 0);
    }
    __builtin_amdgcn_s_setprio(0);

    // ---- mask (diag tiles) + online softmax in exp2 domain
    const int kv0 = kt * 64;
    if (kt >= 2 * qt) {
      const int qg = q0 + w * 32 + l31;
#pragma unroll
      for (int r = 0; r < 16; ++r) {
        int klo = kv0 + (r & 3) + 8 * (r >> 2) + 4 * hi;
        if (klo > qg) s0[r] = -3.0e38f;
        if (klo + 32 > qg) s1[r] = -3.0e38f;
      }
    }
    float rm = s0[0];
#pragma unroll
    for (int r = 1; r < 16; ++r) rm = fmaxf(rm, s0[r]);
#pragma unroll
    for (int r = 0; r < 16; ++r) rm = fmaxf(rm, s1[r]);
    rm = fmaxf(rm, __shfl_xor(rm, 32, 64));
    if (__ballot(rm > mrow + 8.0f)) {       // defer-max: rescale only on real growth
      float mnew = fmaxf(mrow, rm);
      float fct = __builtin_amdgcn_exp2f(mrow - mnew);
      mrow = mnew;
      lrow *= fct;
#pragma unroll
      for (int r = 0; r < 16; ++r) {
        float f = __shfl(fct, (r & 3) + 8 * (r >> 2) + 4 * hi, 64);
        accO[0][r] *= f; accO[1][r] *= f; accO[2][r] *= f; accO[3][r] *= f;
      }
    }
    float ss = 0.f;
#pragma unroll
    for (int r = 0; r < 16; ++r) { float p = __builtin_amdgcn_exp2f(s0[r] - mrow); s0[r] = p; ss += p; }
#pragma unroll
    for (int r = 0; r < 16; ++r) { float p = __builtin_amdgcn_exp2f(s1[r] - mrow); s1[r] = p; ss += p; }
    ss += __shfl_xor(ss, 32, 64);
    lrow += ss;

    // ---- P -> PV A-fragments (in-register, no LDS round trip)
    bf16x8 pa00, pa01, pa10, pa11;
    make_pa(s0, pa00, pa01);   // k slots 0,1 (k=0..31)
    make_pa(s1, pa10, pa11);   // k slots 2,3 (k=32..63)

    // ---- PV: O[32q x 128d] += P[32q x 64k] * V[64k x 128d]
    const char* vl = (const char*)&Vs[cur][0];
    __builtin_amdgcn_s_setprio(1);
#pragma unroll
    for (int dt = 0; dt < 4; ++dt) {
      int R = dt * 16 + (l31 >> 1);
      int cb = (l31 & 1) << 3;      // d-half*8
      int rx = R & 15;
      bf16x8 v00 = *(const bf16x8*)(vl + R * 256 + (((cb + 0 + hi) ^ rx) << 4));
      accO[dt] = __builtin_amdgcn_mfma_f32_32x32x16_bf16(pa00, v00, accO[dt], 0, 0, 0);
      bf16x8 v01 = *(const bf16x8*)(vl + R * 256 + (((cb + 2 + hi) ^ rx) << 4));
      accO[dt] = __builtin_amdgcn_mfma_f32_32x32x16_bf16(pa01, v01, accO[dt], 0, 0, 0);
      bf16x8 v10 = *(const bf16x8*)(vl + R * 256 + (((cb + 4 + hi) ^ rx) << 4));
      accO[dt] = __builtin_amdgcn_mfma_f32_32x32x16_bf16(pa10, v10, accO[dt], 0, 0, 0);
      bf16x8 v11 = *(const bf16x8*)(vl + R * 256 + (((cb + 6 + hi) ^ rx) << 4));
      accO[dt] = __builtin_amdgcn_mfma_f32_32x32x16_bf16(pa11, v11, accO[dt], 0, 0, 0);
    }
    __builtin_amdgcn_s_setprio(0);
  }

  // ---- normalize + write attn out as [b, s, h*128+d] bf16
  const int b = bh >> 4, h = bh & 15;
#pragma unroll
  for (int r = 0; r < 16; ++r) {
    int qr = (r & 3) + 8 * (r >> 2) + 4 * hi;
    float inv = __builtin_amdgcn_rcpf(__shfl(lrow, qr, 64));
    int srow = q0 + w * 32 + qr;
    bf16_t* orow = aout + ((size_t)(b * SS + srow)) * DM + h * HD + l31;
    orow[0]  = (bf16_t)(accO[0][r] * inv);
    orow[32] = (bf16_t)(accO[1][r] * inv);
    orow[64] = (bf16_t)(accO[2][r] * inv);
    orow[96] = (bf16_t)(accO[3][r] * inv);
  }
}

// ---------------- launch ---------------------------------------------------
extern "C" void kernel_launch(void* const* d_in, const int* in_sizes, int n_in,
                              void* d_out, int out_size, void* d_ws, size_t ws_size,
                              hipStream_t stream) {
  (void)in_sizes; (void)n_in; (void)out_size; (void)ws_size;
  const float* x  = (const float*)d_in[0];
  const float* Wq = (const float*)d_in[1];
  const float* Wk = (const float*)d_in[2];
  const float* Wv = (const float*)d_in[3];
  const float* Wo = (const float*)d_in[4];

  float* y  = (float*)d_out;                       // [8192, 2048] fp32
  float* kf = y + (size_t)BS * DM;                 // fp32 [b,h,s,d] (output)
  float* vf = kf + (size_t)BS * DM;                // fp32 [b,h,s,d] (output)

  // ws (max 96MB live):
  //  [0,32M)  xbf (conv->gemm1), then abf (attn out -> out-proj)
  //  [32,64M) qbf (gemm1->attn), then wobf (after attn -> out-proj)
  //  [64,88M) wqkv (conv->gemm1)
  // d_out y region doubles as: kbt bf16 [0,32M of y), vtb bf16 V^T [32,64M of y)
  // (both dead once attn completes; y written last by gemm0)
  char* ws = (char*)d_ws;
  bf16_t* xbf  = (bf16_t*)ws;
  bf16_t* abf  = xbf;
  bf16_t* qbf  = (bf16_t*)(ws + (size_t)32 * 1024 * 1024);
  bf16_t* wobf = qbf;
  bf16_t* wqkv = (bf16_t*)(ws + (size_t)64 * 1024 * 1024);
  bf16_t* kbt  = (bf16_t*)y;
  bf16_t* vtb  = (bf16_t*)((char*)y + (size_t)32 * 1024 * 1024);

  conv_f32_bf16<<<2048, 256, 0, stream>>>(x, (unsigned short*)xbf, BS * DM / 4);
  conv_f32_bf16<<<512, 256, 0, stream>>>(Wq, (unsigned short*)wqkv, DM * DM / 4);
  conv_f32_bf16<<<512, 256, 0, stream>>>(Wk, (unsigned short*)(wqkv + (size_t)DM * DM), DM * DM / 4);
  conv_f32_bf16<<<512, 256, 0, stream>>>(Wv, (unsigned short*)(wqkv + 2 * (size_t)DM * DM), DM * DM / 4);

  // QKV projection: M=8192 (32 M-blocks), N=6144 (24 N-blocks) -> 768 wgs
  gemm8p<1><<<768, 512, 0, stream>>>(
      xbf, wqkv, DM, NQKV, 32, nullptr, qbf, kbt, kf, vf, vtb);

  attn_fwd4<<<1024, 256, 0, stream>>>(qbf, kbt, vtb, abf);

  conv_f32_bf16<<<512, 256, 0, stream>>>(Wo, (unsigned short*)wobf, DM * DM / 4);

  // out-proj: M=8192 (32), N=2048 (8) -> 256 wgs
  gemm8p<0><<<256, 512, 0, stream>>>(
      abf, wobf, DM, DM, 32, y, nullptr, nullptr, nullptr, nullptr, nullptr);
}